// Round 12
// baseline (259.638 us; speedup 1.0000x reference)
//
#include <hip/hip_runtime.h>

// Problem constants
#define EDIM   768
#define E3     2304
#define HIDD   150
#define TT     2048
#define SS     96
#define BB     2

typedef unsigned short u16;
using frag   = __attribute__((ext_vector_type(8))) short;   // 8 bf16 = 4 VGPR
using f32x4v = __attribute__((ext_vector_type(4))) float;   // 4 fp32 acc
using u16x8  = __attribute__((ext_vector_type(8))) unsigned short;

__device__ __forceinline__ u16 bf16rn(float f) {
    union { float f; unsigned u; } v; v.f = f;
    unsigned r = v.u + 0x7FFF + ((v.u >> 16) & 1);
    return (u16)(r >> 16);
}
__device__ __forceinline__ float bf16tof(u16 h) {
    union { unsigned u; float f; } v; v.u = ((unsigned)h) << 16;
    return v.f;
}
__device__ __forceinline__ void split2(float f, u16& hi, u16& lo) {
    hi = bf16rn(f); lo = bf16rn(f - bf16tof(hi));
}
// pairmm LDS swizzle: chunk (row, qd) -> u16 offset. Zero conflicts (r7-measured).
__device__ __forceinline__ int swzoff(int row, int qd) {
    return row * 32 + (((qd + (row >> 1)) & 3) << 3);
}
// async 16B global->LDS copy (per-lane src, dest = uniform base + lane*16)
__device__ __forceinline__ void async16(const void* g, void* l) {
    __builtin_amdgcn_global_load_lds(
        (const __attribute__((address_space(1))) void*)g,
        (__attribute__((address_space(3))) void*)l, 16, 0, 0);
}

// ---------------------------------------------------------------------------
// k_prep_all: fused weight prep.
// blocks [0,720):    W12t transpose (kb = bi%36, nb = bi/36)
// blocks [720,1488): AW1t column k = bi-720
// blocks [1488,1968): AW2t (0) / PW2t (1) / MW2t (2), k = (bi-1488)%160
// ---------------------------------------------------------------------------
__global__ __launch_bounds__(256) void k_prep_all(
    const float* __restrict__ pw1, const float* __restrict__ mw1,
    const float* __restrict__ aw1, const float* __restrict__ aw2,
    const float* __restrict__ pw2, const float* __restrict__ mw2,
    u16* __restrict__ W12t_hi, u16* __restrict__ W12t_lo,
    u16* __restrict__ AW1t_hi, u16* __restrict__ AW1t_lo,
    u16* __restrict__ AW2t_hi, u16* __restrict__ AW2t_lo,
    u16* __restrict__ PW2t_hi, u16* __restrict__ PW2t_lo,
    u16* __restrict__ MW2t_hi, u16* __restrict__ MW2t_lo)
{
    __shared__ float tile[64][33];
    const int bi = blockIdx.x;
    const int t  = threadIdx.x;

    if (bi < 720) {
        const int k0 = (bi % 36) * 64;
        const int n0 = (bi / 36) * 32;
        const int seg = n0 / 160;
        const int nloc0 = n0 - seg * 160;
        for (int idx = t; idx < 2048; idx += 256) {
            const int kk = idx >> 5, nn = idx & 31;
            const int nl = nloc0 + nn;
            const int k  = k0 + kk;
            float v = 0.f;
            if (nl < HIDD) {
                if (seg == 0)      v = pw1[(long)k * HIDD + nl];
                else if (seg == 1) v = pw1[(long)(E3 + k) * HIDD + nl];
                else if (seg == 2) v = mw1[(long)k * HIDD + nl];
                else               v = pw1[(long)(2 * E3 + k) * HIDD + nl];
            }
            tile[kk][nn] = v;
        }
        __syncthreads();
        for (int idx = t; idx < 2048; idx += 256) {
            const int nn = idx >> 6, kk = idx & 63;
            u16 hi, lo; split2(tile[kk][nn], hi, lo);
            W12t_hi[(long)(n0 + nn) * E3 + k0 + kk] = hi;
            W12t_lo[(long)(n0 + nn) * E3 + k0 + kk] = lo;
        }
    } else if (bi < 1488) {
        const int k = bi - 720;
        if (t < 160) {
            float v = (t < HIDD) ? aw1[k * HIDD + t] : 0.f;
            u16 hi, lo; split2(v, hi, lo);
            AW1t_hi[(long)t * EDIM + k] = hi;
            AW1t_lo[(long)t * EDIM + k] = lo;
        }
    } else {
        const int r = bi - 1488;
        const int k = r % 160;
        const int which = r / 160;
        const float* src = (which == 0) ? aw2 : (which == 1) ? pw2 : mw2;
        u16* dh = (which == 0) ? AW2t_hi : (which == 1) ? PW2t_hi : MW2t_hi;
        u16* dl = (which == 0) ? AW2t_lo : (which == 1) ? PW2t_lo : MW2t_lo;
        if (t < 160) {
            float v = (t < HIDD && k < HIDD) ? src[k * HIDD + t] : 0.f;
            u16 hi, lo; split2(v, hi, lo);
            dh[t * 160 + k] = hi;
            dl[t * 160 + k] = lo;
        }
    }
}

// ---------------------------------------------------------------------------
// k_attn1: layer-1 K-split. Grid (48 rowblocks, 4 ksplit), 256 thr.
// ---------------------------------------------------------------------------
__global__ __launch_bounds__(256) void k_attn1(
    const float* __restrict__ X, const int* __restrict__ spans,
    const u16* __restrict__ AW1t_hi, const u16* __restrict__ AW1t_lo,
    float* __restrict__ AH1)
{
    __shared__ __align__(16) u16 As_hi[32 * 40];
    __shared__ __align__(16) u16 As_lo[32 * 40];
    __shared__ __align__(16) u16 Bs_hi[160 * 40];
    __shared__ __align__(16) u16 Bs_lo[160 * 40];

    const int t    = threadIdx.x;
    const int lane = t & 63;
    const int m    = lane & 15;
    const int quad = lane >> 4;
    const int w    = t >> 6;
    const int mt   = (w & 1) * 16;
    const int nb   = (w >> 1) * 80;
    const int ks   = blockIdx.y;

    const int rr = t >> 3, q = t & 7;
    const int grow = blockIdx.x * 32 + rr;
    const int bs = grow >> 3, sw = grow & 7;
    const int b  = bs / SS;
    const int tok = spans[bs] + sw;
    const float* arow = X + ((long)b * TT + tok) * EDIM;

    f32x4v acc[5];
    #pragma unroll
    for (int ht = 0; ht < 5; ++ht)
        #pragma unroll
        for (int r = 0; r < 4; ++r) acc[ht][r] = 0.f;

    for (int tt = 0; tt < 6; ++tt) {
        const int kk0 = ks * 192 + tt * 32;
        {
            const float4 xv = *(const float4*)&arow[kk0 + q * 4];
            ushort4 hv, lv;
            split2(xv.x, hv.x, lv.x); split2(xv.y, hv.y, lv.y);
            split2(xv.z, hv.z, lv.z); split2(xv.w, hv.w, lv.w);
            *(ushort4*)&As_hi[rr * 40 + q * 4] = hv;
            *(ushort4*)&As_lo[rr * 40 + q * 4] = lv;
        }
        #pragma unroll
        for (int it = 0; it < 3; ++it) {
            const int v = t + it * 256;
            if (v < 640) {
                const int h = v >> 2, qq = v & 3;
                *(uint4*)&Bs_hi[h * 40 + qq * 8] = *(const uint4*)&AW1t_hi[(long)h * EDIM + kk0 + qq * 8];
                *(uint4*)&Bs_lo[h * 40 + qq * 8] = *(const uint4*)&AW1t_lo[(long)h * EDIM + kk0 + qq * 8];
            }
        }
        __syncthreads();
        const frag ah = *(const frag*)&As_hi[(mt + m) * 40 + quad * 8];
        const frag al = *(const frag*)&As_lo[(mt + m) * 40 + quad * 8];
        #pragma unroll
        for (int ht = 0; ht < 5; ++ht) {
            const frag bh = *(const frag*)&Bs_hi[(nb + ht * 16 + m) * 40 + quad * 8];
            const frag bl = *(const frag*)&Bs_lo[(nb + ht * 16 + m) * 40 + quad * 8];
            acc[ht] = __builtin_amdgcn_mfma_f32_16x16x32_bf16(al, bh, acc[ht], 0, 0, 0);
            acc[ht] = __builtin_amdgcn_mfma_f32_16x16x32_bf16(ah, bl, acc[ht], 0, 0, 0);
            acc[ht] = __builtin_amdgcn_mfma_f32_16x16x32_bf16(ah, bh, acc[ht], 0, 0, 0);
        }
        __syncthreads();
    }
    #pragma unroll
    for (int ht = 0; ht < 5; ++ht) {
        #pragma unroll
        for (int r = 0; r < 4; ++r) {
            const int row = blockIdx.x * 32 + mt + quad * 4 + r;
            const int col = nb + ht * 16 + m;
            if (col < HIDD) atomicAdd(&AH1[row * 160 + col], acc[ht][r]);
        }
    }
}

// ---------------------------------------------------------------------------
// k_attn2: bias+relu on rows, layer2 MFMA, layer3 dot.
// GENERIC over [32-row blocks x 160] @ W2t[160x160] + w3 dot -> out[row].
// Used for attn (grid 48) AND mention (grid 6, with M/MW2t/mb*/mw3).
// ---------------------------------------------------------------------------
__global__ __launch_bounds__(256) void k_attn2(
    const float* __restrict__ AH1,
    const u16* __restrict__ AW2t_hi, const u16* __restrict__ AW2t_lo,
    const float* __restrict__ ab1, const float* __restrict__ ab2,
    const float* __restrict__ aw3, const float* __restrict__ ab3,
    float* __restrict__ attn_g)
{
    __shared__ __align__(16) u16 As_hi[32 * 40];
    __shared__ __align__(16) u16 As_lo[32 * 40];
    __shared__ __align__(16) u16 Bs_hi[160 * 40];
    __shared__ __align__(16) u16 Bs_lo[160 * 40];
    __shared__ float h1s[32 * 160];
    __shared__ float red[32];

    const int t    = threadIdx.x;
    const int lane = t & 63;
    const int m    = lane & 15;
    const int quad = lane >> 4;
    const int w    = t >> 6;
    const int mt   = (w & 1) * 16;
    const int nb   = (w >> 1) * 80;

    for (int u = t; u < 1280; u += 256) {
        const int row = u / 40, c4 = u - (u / 40) * 40;
        const int c0 = c4 * 4;
        const float4 v = *(const float4*)&AH1[(blockIdx.x * 32 + row) * 160 + c0];
        h1s[row * 160 + c0 + 0] = (c0 + 0 < HIDD) ? fmaxf(v.x + ab1[c0 + 0], 0.f) : 0.f;
        h1s[row * 160 + c0 + 1] = (c0 + 1 < HIDD) ? fmaxf(v.y + ab1[c0 + 1], 0.f) : 0.f;
        h1s[row * 160 + c0 + 2] = (c0 + 2 < HIDD) ? fmaxf(v.z + ab1[c0 + 2], 0.f) : 0.f;
        h1s[row * 160 + c0 + 3] = (c0 + 3 < HIDD) ? fmaxf(v.w + ab1[c0 + 3], 0.f) : 0.f;
    }
    if (t < 32) red[t] = 0.f;
    __syncthreads();

    const int rr = t >> 3, q = t & 7;
    f32x4v acc2[5];
    #pragma unroll
    for (int ht = 0; ht < 5; ++ht)
        #pragma unroll
        for (int r = 0; r < 4; ++r) acc2[ht][r] = 0.f;

    for (int kk = 0; kk < 5; ++kk) {
        {
            const float4 xv = *(const float4*)&h1s[rr * 160 + kk * 32 + q * 4];
            ushort4 hv, lv;
            split2(xv.x, hv.x, lv.x); split2(xv.y, hv.y, lv.y);
            split2(xv.z, hv.z, lv.z); split2(xv.w, hv.w, lv.w);
            *(ushort4*)&As_hi[rr * 40 + q * 4] = hv;
            *(ushort4*)&As_lo[rr * 40 + q * 4] = lv;
        }
        #pragma unroll
        for (int it = 0; it < 3; ++it) {
            const int v = t + it * 256;
            if (v < 640) {
                const int h = v >> 2, qq = v & 3;
                *(uint4*)&Bs_hi[h * 40 + qq * 8] = *(const uint4*)&AW2t_hi[h * 160 + kk * 32 + qq * 8];
                *(uint4*)&Bs_lo[h * 40 + qq * 8] = *(const uint4*)&AW2t_lo[h * 160 + kk * 32 + qq * 8];
            }
        }
        __syncthreads();
        const frag ah = *(const frag*)&As_hi[(mt + m) * 40 + quad * 8];
        const frag al = *(const frag*)&As_lo[(mt + m) * 40 + quad * 8];
        #pragma unroll
        for (int ht = 0; ht < 5; ++ht) {
            const frag bh = *(const frag*)&Bs_hi[(nb + ht * 16 + m) * 40 + quad * 8];
            const frag bl = *(const frag*)&Bs_lo[(nb + ht * 16 + m) * 40 + quad * 8];
            acc2[ht] = __builtin_amdgcn_mfma_f32_16x16x32_bf16(al, bh, acc2[ht], 0, 0, 0);
            acc2[ht] = __builtin_amdgcn_mfma_f32_16x16x32_bf16(ah, bl, acc2[ht], 0, 0, 0);
            acc2[ht] = __builtin_amdgcn_mfma_f32_16x16x32_bf16(ah, bh, acc2[ht], 0, 0, 0);
        }
        __syncthreads();
    }

    float s[4] = {0.f, 0.f, 0.f, 0.f};
    #pragma unroll
    for (int ht = 0; ht < 5; ++ht) {
        const int col = nb + ht * 16 + m;
        if (col < HIDD) {
            const float w3 = aw3[col];
            #pragma unroll
            for (int r = 0; r < 4; ++r)
                s[r] += fmaxf(acc2[ht][r] + ab2[col], 0.f) * w3;
        }
    }
    #pragma unroll
    for (int r = 0; r < 4; ++r) {
        for (int off = 8; off > 0; off >>= 1) s[r] += __shfl_down(s[r], off, 16);
    }
    if (m == 0) {
        #pragma unroll
        for (int r = 0; r < 4; ++r) atomicAdd(&red[mt + quad * 4 + r], s[r]);
    }
    __syncthreads();
    if (t < 32) attn_g[blockIdx.x * 32 + t] = red[t] + ab3[0];
}

// ---------------------------------------------------------------------------
// k_span_g: build g_i fp32 (G_ws) AND bf16 hi/lo split (Gs_hi/lo). 192 blocks.
// ---------------------------------------------------------------------------
__global__ __launch_bounds__(256) void k_span_g(
    const float* __restrict__ X, const int* __restrict__ spans,
    const float* __restrict__ attn_g, float* __restrict__ G_ws,
    u16* __restrict__ Gs_hi, u16* __restrict__ Gs_lo)
{
    __shared__ float a8[8];
    const int t  = threadIdx.x;
    const int bs = blockIdx.x;
    const int b  = bs / SS;
    const int start = spans[bs];
    const float* xb = X + ((long)b * TT + start) * EDIM;
    float* Gp = G_ws + (long)bs * E3;
    u16* Gh = Gs_hi + (long)bs * E3;
    u16* Gl = Gs_lo + (long)bs * E3;
    if (t < 8) a8[t] = attn_g[bs * 8 + t];
    __syncthreads();

    for (int e = t; e < EDIM; e += 256) {
        const float gs = xb[e];
        const float ge = xb[7 * EDIM + e];
        float ga = 0.f;
        #pragma unroll
        for (int w = 0; w < 8; ++w) ga += xb[w * EDIM + e] * a8[w];
        Gp[e] = gs; Gp[EDIM + e] = ge; Gp[2 * EDIM + e] = ga;
        u16 hi, lo;
        split2(gs, hi, lo); Gh[e] = hi;            Gl[e] = lo;
        split2(ge, hi, lo); Gh[EDIM + e] = hi;     Gl[EDIM + e] = lo;
        split2(ga, hi, lo); Gh[2 * EDIM + e] = hi; Gl[2 * EDIM + e] = lo;
    }
}

// ---------------------------------------------------------------------------
// k_uvm: MFMA GEMM [192x2304] @ W12t(rows 0..480)^T -> UVM[3][192][160].
// Grid (3, 3, 12) = 108 blocks, 6 iters each.
// ---------------------------------------------------------------------------
__global__ __launch_bounds__(256) void k_uvm(
    const u16* __restrict__ Gs_hi, const u16* __restrict__ Gs_lo,
    const u16* __restrict__ W9t_hi, const u16* __restrict__ W9t_lo,
    float* __restrict__ UVM)
{
    __shared__ __align__(16) u16 As_hi[64 * 40];
    __shared__ __align__(16) u16 As_lo[64 * 40];
    __shared__ __align__(16) u16 Bs_hi[160 * 40];
    __shared__ __align__(16) u16 Bs_lo[160 * 40];

    const int t    = threadIdx.x;
    const int mb   = blockIdx.x;
    const int nb   = blockIdx.y;
    const int ks   = blockIdx.z;
    const int lane = t & 63;
    const int m    = lane & 15;
    const int quad = lane >> 4;
    const int w    = t >> 6;
    const int mhalf = (w & 1) * 32;
    const int nbase = (w >> 1) * 80;
    const int arr = t >> 2, aq = t & 3;

    f32x4v acc[2][5];
    #pragma unroll
    for (int i = 0; i < 2; ++i)
        #pragma unroll
        for (int j = 0; j < 5; ++j)
            #pragma unroll
            for (int r = 0; r < 4; ++r) acc[i][j][r] = 0.f;

    for (int tt = 0; tt < 6; ++tt) {
        const int kk0 = ks * 192 + tt * 32;
        *(uint4*)&As_hi[arr * 40 + aq * 8] = *(const uint4*)&Gs_hi[(long)(mb * 64 + arr) * E3 + kk0 + aq * 8];
        *(uint4*)&As_lo[arr * 40 + aq * 8] = *(const uint4*)&Gs_lo[(long)(mb * 64 + arr) * E3 + kk0 + aq * 8];
        #pragma unroll
        for (int it = 0; it < 3; ++it) {
            const int v = t + it * 256;
            if (v < 640) {
                const int h = v >> 2, qq = v & 3;
                *(uint4*)&Bs_hi[h * 40 + qq * 8] = *(const uint4*)&W9t_hi[(long)(nb * 160 + h) * E3 + kk0 + qq * 8];
                *(uint4*)&Bs_lo[h * 40 + qq * 8] = *(const uint4*)&W9t_lo[(long)(nb * 160 + h) * E3 + kk0 + qq * 8];
            }
        }
        __syncthreads();
        frag ah[2], al[2];
        #pragma unroll
        for (int mt = 0; mt < 2; ++mt) {
            ah[mt] = *(const frag*)&As_hi[(mhalf + mt * 16 + m) * 40 + quad * 8];
            al[mt] = *(const frag*)&As_lo[(mhalf + mt * 16 + m) * 40 + quad * 8];
        }
        #pragma unroll
        for (int ht = 0; ht < 5; ++ht) {
            const frag bh = *(const frag*)&Bs_hi[(nbase + ht * 16 + m) * 40 + quad * 8];
            const frag bl = *(const frag*)&Bs_lo[(nbase + ht * 16 + m) * 40 + quad * 8];
            #pragma unroll
            for (int mt = 0; mt < 2; ++mt) {
                acc[mt][ht] = __builtin_amdgcn_mfma_f32_16x16x32_bf16(al[mt], bh, acc[mt][ht], 0, 0, 0);
                acc[mt][ht] = __builtin_amdgcn_mfma_f32_16x16x32_bf16(ah[mt], bl, acc[mt][ht], 0, 0, 0);
                acc[mt][ht] = __builtin_amdgcn_mfma_f32_16x16x32_bf16(ah[mt], bh, acc[mt][ht], 0, 0, 0);
            }
        }
        __syncthreads();
    }
    float* dst = UVM + (long)nb * (192 * 160);
    #pragma unroll
    for (int mt = 0; mt < 2; ++mt) {
        #pragma unroll
        for (int ht = 0; ht < 5; ++ht) {
            #pragma unroll
            for (int r = 0; r < 4; ++r) {
                const int row = mb * 64 + mhalf + mt * 16 + quad * 4 + r;
                const int c   = nbase + ht * 16 + m;
                atomicAdd(&dst[row * 160 + c], acc[mt][ht][r]);
            }
        }
    }
}

// ---------------------------------------------------------------------------
// k_pairmm: MFMA bilinear, symmetric, async DMA staging, single-buffered.
// Deep-K variant: nks = gridDim.x (3 or 4), k-chunks per block = 72/nks.
// Grid (nks, 96, 2). LDS 48 KB -> 3 blocks/CU; nks=4 gives 768 blocks = 3/CU.
// Plain stores into per-ks partial buffers (summed by k_pair2).
// ---------------------------------------------------------------------------
__global__ __launch_bounds__(256) void k_pairmm(
    const float* __restrict__ G_ws,
    const u16* __restrict__ PCt_hi, const u16* __restrict__ PCt_lo,
    float* __restrict__ H1parts)
{
    __shared__ float gis[768];
    __shared__ __align__(16) float gjst[96 * 32];        // 12 KB raw gj tile
    __shared__ __align__(16) u16 As_hi[96 * 32];
    __shared__ __align__(16) u16 As_lo[96 * 32];
    __shared__ __align__(16) u16 Bs_hi[160 * 32];
    __shared__ __align__(16) u16 Bs_lo[160 * 32];

    const int t   = threadIdx.x;
    const int ks  = blockIdx.x;
    const int nks = gridDim.x;
    const int KCH = 72 / nks;            // k-chunks (of 32) per block
    const int i  = blockIdx.y;
    const int b  = blockIdx.z;
    const int ksbase = ks * KCH * 32;
    const int jt0 = i >> 4;
    const int ntiles = 6 - jt0;
    const int j0 = jt0 * 16;
    const int R  = 96 - j0;
    const int nI = R >> 3;               // gj DMA instrs (R/8)

    const int lane = t & 63;
    const int m    = lane & 15;
    const int quad = lane >> 4;
    const int w    = t >> 6;
    const int hb   = (w & 1) * 80;       // B row half
    const int apar = w >> 1;             // tile parity

    const int Bl_h  = lane >> 2;
    const int Bl_c  = lane & 3;
    const int gj_r  = lane >> 3;
    const int gj_c  = lane & 7;

    const float* Gi = G_ws + (long)(b * SS + i) * E3 + ksbase;
    for (int e = t; e < KCH * 32; e += 256) gis[e] = Gi[e];

    f32x4v acc[3][5];
    #pragma unroll
    for (int jt = 0; jt < 3; ++jt)
        #pragma unroll
        for (int ht = 0; ht < 5; ++ht)
            #pragma unroll
            for (int r = 0; r < 4; ++r) acc[jt][ht][r] = 0.f;

    for (int tt = 0; tt < KCH; ++tt) {
        const int kk0 = ksbase + tt * 32;
        for (int q2 = w; q2 < 10; q2 += 4) {
            const int h  = q2 * 16 + Bl_h;
            const int qd = (Bl_c - (h >> 1)) & 3;
            const long so = (long)h * E3 + kk0 + qd * 8;
            async16(&PCt_hi[so], &Bs_hi[q2 * 512]);
            async16(&PCt_lo[so], &Bs_lo[q2 * 512]);
        }
        for (int g2 = w; g2 < nI; g2 += 4) {
            const int row = j0 + g2 * 8 + gj_r;
            async16(&G_ws[(long)(b * SS + row) * E3 + kk0 + gj_c * 4],
                    &gjst[g2 * 256]);
        }
        __syncthreads();   // drains vmcnt (DMA) + orders LDS

        for (int u = t; u < R * 4; u += 256) {
            const int rr = u >> 2, qd = u & 3;
            const float4 g0 = *(const float4*)&gjst[rr * 32 + qd * 8];
            const float4 g1 = *(const float4*)&gjst[rr * 32 + qd * 8 + 4];
            const int kl = tt * 32 + qd * 8;
            u16x8 hv, lv; u16 h, l;
            split2(g0.x * gis[kl + 0], h, l); hv[0] = h; lv[0] = l;
            split2(g0.y * gis[kl + 1], h, l); hv[1] = h; lv[1] = l;
            split2(g0.z * gis[kl + 2], h, l); hv[2] = h; lv[2] = l;
            split2(g0.w * gis[kl + 3], h, l); hv[3] = h; lv[3] = l;
            split2(g1.x * gis[kl + 4], h, l); hv[4] = h; lv[4] = l;
            split2(g1.y * gis[kl + 5], h, l); hv[5] = h; lv[5] = l;
            split2(g1.z * gis[kl + 6], h, l); hv[6] = h; lv[6] = l;
            split2(g1.w * gis[kl + 7], h, l); hv[7] = h; lv[7] = l;
            const int o = swzoff(rr, qd);
            *(u16x8*)&As_hi[o] = hv;
            *(u16x8*)&As_lo[o] = lv;
        }
        __syncthreads();

        frag ah[3], al[3];
        #pragma unroll
        for (int u = 0; u < 3; ++u) {
            const int a = apar + 2 * u;
            if (a < ntiles) {
                const int o = swzoff(a * 16 + m, quad);
                ah[u] = *(const frag*)&As_hi[o];
                al[u] = *(const frag*)&As_lo[o];
            }
        }
        #pragma unroll
        for (int ht = 0; ht < 5; ++ht) {
            const int o = swzoff(hb + ht * 16 + m, quad);
            const frag bh = *(const frag*)&Bs_hi[o];
            const frag bl = *(const frag*)&Bs_lo[o];
            #pragma unroll
            for (int u = 0; u < 3; ++u) {
                if (apar + 2 * u < ntiles) {
                    acc[u][ht] = __builtin_amdgcn_mfma_f32_16x16x32_bf16(al[u], bh, acc[u][ht], 0, 0, 0);
                    acc[u][ht] = __builtin_amdgcn_mfma_f32_16x16x32_bf16(ah[u], bl, acc[u][ht], 0, 0, 0);
                    acc[u][ht] = __builtin_amdgcn_mfma_f32_16x16x32_bf16(ah[u], bh, acc[u][ht], 0, 0, 0);
                }
            }
        }
        __syncthreads();
    }

    float* dst = H1parts + (long)ks * ((long)BB * SS * SS * 160);
    #pragma unroll
    for (int u = 0; u < 3; ++u) {
        const int a = apar + 2 * u;
        if (a < ntiles) {
            #pragma unroll
            for (int ht = 0; ht < 5; ++ht) {
                #pragma unroll
                for (int r = 0; r < 4; ++r) {
                    const int j = (jt0 + a) * 16 + quad * 4 + r;
                    const int h = hb + ht * 16 + m;
                    dst[((long)(b * SS + i) * SS + j) * 160 + h] = acc[u][ht][r];
                }
            }
        }
    }
}

// ---------------------------------------------------------------------------
// k_pair2: MFMA finish; sums nparts H1 parts at [min(i,j)*96+max(i,j)].
// ---------------------------------------------------------------------------
__global__ __launch_bounds__(256) void k_pair2(
    const float* __restrict__ H1parts, const int nparts,
    const float* __restrict__ U_ws, const float* __restrict__ V_ws,
    const float* __restrict__ pb1, const float* __restrict__ m_ws,
    const u16* __restrict__ PW2t_hi, const u16* __restrict__ PW2t_lo,
    const float* __restrict__ pb2, const float* __restrict__ pw3,
    const float* __restrict__ pb3,
    float* __restrict__ out)
{
    __shared__ __align__(16) u16 As_hi[96 * 168];
    __shared__ __align__(16) u16 As_lo[96 * 168];
    __shared__ __align__(16) u16 Bs_hi[160 * 40];
    __shared__ __align__(16) u16 Bs_lo[160 * 40];
    __shared__ float uv[160];
    __shared__ float red[96];

    const long partsz = (long)BB * SS * SS * 160;
    const int t  = threadIdx.x;
    const int bi = blockIdx.x;          // b*96 + i
    const int b  = bi / SS;
    const int ii = bi - b * SS;

    if (t < 160) uv[t] = U_ws[bi * 160 + t] + ((t < HIDD) ? pb1[t] : 0.f);
    if (t < 96) red[t] = 0.f;
    __syncthreads();

    for (int u = t; u < 96 * 40; u += 256) {
        const int j = u / 40, hq = u - (u / 40) * 40;
        const int h0 = hq * 4;
        const int mn = ii < j ? ii : j;
        const int mx = ii < j ? j : ii;
        const long idx = (((long)b * SS + mn) * SS + mx) * 160 + h0;
        const float4 vv = *(const float4*)&V_ws[(b * SS + j) * 160 + h0];
        float p0 = vv.x + uv[h0 + 0];
        float p1 = vv.y + uv[h0 + 1];
        float p2 = vv.z + uv[h0 + 2];
        float p3 = vv.w + uv[h0 + 3];
        for (int pp = 0; pp < nparts; ++pp) {
            const float4 a = *(const float4*)&H1parts[pp * partsz + idx];
            p0 += a.x; p1 += a.y; p2 += a.z; p3 += a.w;
        }
        p0 = fmaxf(p0, 0.f); p1 = fmaxf(p1, 0.f);
        p2 = fmaxf(p2, 0.f); p3 = fmaxf(p3, 0.f);
        ushort4 hv, lv;
        split2(p0, hv.x, lv.x); split2(p1, hv.y, lv.y);
        split2(p2, hv.z, lv.z); split2(p3, hv.w, lv.w);
        *(ushort4*)&As_hi[j * 168 + h0] = hv;
        *(ushort4*)&As_lo[j * 168 + h0] = lv;
    }
    __syncthreads();

    const int lane = t & 63;
    const int m    = lane & 15;
    const int quad = lane >> 4;
    const int w    = t >> 6;
    const int jbs  = (w & 1) * 48;
    const int nbs  = (w >> 1) * 80;

    f32x4v acc[3][5];
    #pragma unroll
    for (int jt = 0; jt < 3; ++jt)
        #pragma unroll
        for (int ht = 0; ht < 5; ++ht)
            #pragma unroll
            for (int r = 0; r < 4; ++r) acc[jt][ht][r] = 0.f;

    for (int kk = 0; kk < 5; ++kk) {
        #pragma unroll
        for (int it = 0; it < 3; ++it) {
            const int v = t + it * 256;
            if (v < 640) {
                const int n = v >> 2, qq = v & 3;
                *(uint4*)&Bs_hi[n * 40 + qq * 8] = *(const uint4*)&PW2t_hi[n * 160 + kk * 32 + qq * 8];
                *(uint4*)&Bs_lo[n * 40 + qq * 8] = *(const uint4*)&PW2t_lo[n * 160 + kk * 32 + qq * 8];
            }
        }
        __syncthreads();
        frag ah[3], al[3];
        #pragma unroll
        for (int jt = 0; jt < 3; ++jt) {
            ah[jt] = *(const frag*)&As_hi[(jbs + jt * 16 + m) * 168 + kk * 32 + quad * 8];
            al[jt] = *(const frag*)&As_lo[(jbs + jt * 16 + m) * 168 + kk * 32 + quad * 8];
        }
        #pragma unroll
        for (int ht = 0; ht < 5; ++ht) {
            const frag bh = *(const frag*)&Bs_hi[(nbs + ht * 16 + m) * 40 + quad * 8];
            const frag bl = *(const frag*)&Bs_lo[(nbs + ht * 16 + m) * 40 + quad * 8];
            #pragma unroll
            for (int jt = 0; jt < 3; ++jt) {
                acc[jt][ht] = __builtin_amdgcn_mfma_f32_16x16x32_bf16(al[jt], bh, acc[jt][ht], 0, 0, 0);
                acc[jt][ht] = __builtin_amdgcn_mfma_f32_16x16x32_bf16(ah[jt], bl, acc[jt][ht], 0, 0, 0);
                acc[jt][ht] = __builtin_amdgcn_mfma_f32_16x16x32_bf16(ah[jt], bh, acc[jt][ht], 0, 0, 0);
            }
        }
        __syncthreads();
    }

    float s[3][4];
    #pragma unroll
    for (int jt = 0; jt < 3; ++jt)
        #pragma unroll
        for (int r = 0; r < 4; ++r) s[jt][r] = 0.f;
    #pragma unroll
    for (int ht = 0; ht < 5; ++ht) {
        const int col = nbs + ht * 16 + m;
        if (col < HIDD) {
            const float w3 = pw3[col];
            const float b2 = pb2[col];
            #pragma unroll
            for (int jt = 0; jt < 3; ++jt)
                #pragma unroll
                for (int r = 0; r < 4; ++r)
                    s[jt][r] += fmaxf(acc[jt][ht][r] + b2, 0.f) * w3;
        }
    }
    #pragma unroll
    for (int jt = 0; jt < 3; ++jt)
        #pragma unroll
        for (int r = 0; r < 4; ++r)
            for (int off = 8; off > 0; off >>= 1)
                s[jt][r] += __shfl_down(s[jt][r], off, 16);
    if (m == 0) {
        #pragma unroll
        for (int jt = 0; jt < 3; ++jt)
            #pragma unroll
            for (int r = 0; r < 4; ++r)
                atomicAdd(&red[jbs + jt * 16 + quad * 4 + r], s[jt][r]);
    }
    __syncthreads();

    if (t < 96) {
        const float sc = red[t] + pb3[0];
        const float v = (m_ws[bi] + m_ws[b * SS + t] + sc) * (1.f / 3.f);
        out[(long)bi * SS + t] = fminf(fmaxf(v, 0.f), 1.f);
    }
}

// ---------------------------------------------------------------------------
extern "C" void kernel_launch(void* const* d_in, const int* in_sizes, int n_in,
                              void* d_out, int out_size, void* d_ws, size_t ws_size,
                              hipStream_t stream)
{
    const float* X     = (const float*)d_in[0];
    const int*   spans = (const int*)  d_in[1];
    const float* aw1 = (const float*)d_in[2];
    const float* ab1 = (const float*)d_in[3];
    const float* aw2 = (const float*)d_in[4];
    const float* ab2 = (const float*)d_in[5];
    const float* aw3 = (const float*)d_in[6];
    const float* ab3 = (const float*)d_in[7];
    const float* mw1 = (const float*)d_in[8];
    const float* mb1 = (const float*)d_in[9];
    const float* mw2 = (const float*)d_in[10];
    const float* mb2 = (const float*)d_in[11];
    const float* mw3 = (const float*)d_in[12];
    const float* mb3 = (const float*)d_in[13];
    const float* pw1 = (const float*)d_in[14];
    const float* pb1 = (const float*)d_in[15];
    const float* pw2 = (const float*)d_in[16];
    const float* pb2 = (const float*)d_in[17];
    const float* pw3 = (const float*)d_in[18];
    const float* pb3 = (const float*)d_in[19];
    float* out = (float*)d_out;

    char* p = (char*)d_ws;
    float* attn_g  = (float*)p;  p += 6144;                       // 1536 f
    float* G_ws    = (float*)p;  p += (long)442368 * 4;           // 192x2304 f
    u16*   Gs_hi   = (u16*)p;    p += (long)442368 * 2;
    u16*   Gs_lo   = (u16*)p;    p += (long)442368 * 2;
    float* UVM     = (float*)p;  p += (long)3 * 192 * 160 * 4;    // U|V|M (zeroed)
    float* AH1     = (float*)p;  p += (long)1536 * 160 * 4;       // attn L1 partials (zeroed)
    float* m_ws    = (float*)p;  p += 1024;
    u16*   W12t_hi = (u16*)p;    p += (long)640 * E3 * 2;         // PA|PB|mw1|PC
    u16*   W12t_lo = (u16*)p;    p += (long)640 * E3 * 2;
    u16*   AW1t_hi = (u16*)p;    p += (long)160 * EDIM * 2;
    u16*   AW1t_lo = (u16*)p;    p += (long)160 * EDIM * 2;
    u16*   AW2t_hi = (u16*)p;    p += 160 * 160 * 2;
    u16*   AW2t_lo = (u16*)p;    p += 160 * 160 * 2;
    u16*   PW2t_hi = (u16*)p;    p += 160 * 160 * 2;
    u16*   PW2t_lo = (u16*)p;    p += 160 * 160 * 2;
    u16*   MW2t_hi = (u16*)p;    p += 160 * 160 * 2;
    u16*   MW2t_lo = (u16*)p;    p += 160 * 160 * 2;
    float* H1parts = (float*)p;   // nks * 11.8 MB

    const long partsz = (long)BB * SS * SS * 160;
    // pick deepest K-split that fits the workspace (4 preferred, else 3)
    const size_t used = (size_t)((char*)H1parts - (char*)d_ws);
    int nks = 4;
    if (used + (size_t)nks * partsz * sizeof(float) > ws_size) nks = 3;

    float* U_ws = UVM;
    float* V_ws = UVM + 192 * 160;
    float* M_ws = UVM + 2 * 192 * 160;
    const u16* PCt_hi = W12t_hi + (long)480 * E3;
    const u16* PCt_lo = W12t_lo + (long)480 * E3;

    // zero UVM + AH1 (contiguous atomic targets)
    hipMemsetAsync(UVM, 0, ((size_t)3 * 192 * 160 + (size_t)1536 * 160) * sizeof(float), stream);

    k_prep_all<<<dim3(1968), 256, 0, stream>>>(pw1, mw1, aw1, aw2, pw2, mw2,
                                               W12t_hi, W12t_lo, AW1t_hi, AW1t_lo,
                                               AW2t_hi, AW2t_lo, PW2t_hi, PW2t_lo,
                                               MW2t_hi, MW2t_lo);

    k_attn1<<<dim3(48, 4), 256, 0, stream>>>(X, spans, AW1t_hi, AW1t_lo, AH1);
    k_attn2<<<dim3(48), 256, 0, stream>>>(AH1, AW2t_hi, AW2t_lo, ab1, ab2, aw3, ab3, attn_g);
    k_span_g<<<dim3(BB * SS), 256, 0, stream>>>(X, spans, attn_g, G_ws, Gs_hi, Gs_lo);
    k_uvm<<<dim3(3, 3, 12), 256, 0, stream>>>(Gs_hi, Gs_lo, W12t_hi, W12t_lo, UVM);
    // mention layers 2-3: identical shape to attn2 -> reuse kernel (grid 6)
    k_attn2<<<dim3(6), 256, 0, stream>>>(M_ws, MW2t_hi, MW2t_lo, mb1, mb2, mw3, mb3, m_ws);
    k_pairmm<<<dim3(nks, SS, BB), 256, 0, stream>>>(G_ws, PCt_hi, PCt_lo, H1parts);

    k_pair2<<<dim3(BB * SS), 256, 0, stream>>>(
        H1parts, nks,
        U_ws, V_ws, pb1, m_ws, PW2t_hi, PW2t_lo, pb2, pw3, pb3, out);
}

// Round 13
// 215.555 us; speedup vs baseline: 1.2045x; 1.2045x over previous
//
#include <hip/hip_runtime.h>

// Problem constants
#define EDIM   768
#define E3     2304
#define HIDD   150
#define TT     2048
#define SS     96
#define BB     2

typedef unsigned short u16;
using frag   = __attribute__((ext_vector_type(8))) short;   // 8 bf16 = 4 VGPR
using f32x4v = __attribute__((ext_vector_type(4))) float;   // 4 fp32 acc
using u16x8  = __attribute__((ext_vector_type(8))) unsigned short;

__device__ __forceinline__ u16 bf16rn(float f) {
    union { float f; unsigned u; } v; v.f = f;
    unsigned r = v.u + 0x7FFF + ((v.u >> 16) & 1);
    return (u16)(r >> 16);
}
__device__ __forceinline__ float bf16tof(u16 h) {
    union { unsigned u; float f; } v; v.u = ((unsigned)h) << 16;
    return v.f;
}
__device__ __forceinline__ void split2(float f, u16& hi, u16& lo) {
    hi = bf16rn(f); lo = bf16rn(f - bf16tof(hi));
}
// pairmm LDS swizzle: chunk (row, qd) -> u16 offset. Zero conflicts (r7-measured).
__device__ __forceinline__ int swzoff(int row, int qd) {
    return row * 32 + (((qd + (row >> 1)) & 3) << 3);
}
// async 16B global->LDS copy (per-lane src, dest = uniform base + lane*16)
__device__ __forceinline__ void async16(const void* g, void* l) {
    __builtin_amdgcn_global_load_lds(
        (const __attribute__((address_space(1))) void*)g,
        (__attribute__((address_space(3))) void*)l, 16, 0, 0);
}

// ---------------------------------------------------------------------------
// k_prep_all: fused weight prep.
// blocks [0,720):    W12t transpose (kb = bi%36, nb = bi/36)
// blocks [720,1488): AW1t column k = bi-720
// blocks [1488,1968): AW2t (0) / PW2t (1) / MW2t (2), k = (bi-1488)%160
// ---------------------------------------------------------------------------
__global__ __launch_bounds__(256) void k_prep_all(
    const float* __restrict__ pw1, const float* __restrict__ mw1,
    const float* __restrict__ aw1, const float* __restrict__ aw2,
    const float* __restrict__ pw2, const float* __restrict__ mw2,
    u16* __restrict__ W12t_hi, u16* __restrict__ W12t_lo,
    u16* __restrict__ AW1t_hi, u16* __restrict__ AW1t_lo,
    u16* __restrict__ AW2t_hi, u16* __restrict__ AW2t_lo,
    u16* __restrict__ PW2t_hi, u16* __restrict__ PW2t_lo,
    u16* __restrict__ MW2t_hi, u16* __restrict__ MW2t_lo)
{
    __shared__ float tile[64][33];
    const int bi = blockIdx.x;
    const int t  = threadIdx.x;

    if (bi < 720) {
        const int k0 = (bi % 36) * 64;
        const int n0 = (bi / 36) * 32;
        const int seg = n0 / 160;
        const int nloc0 = n0 - seg * 160;
        for (int idx = t; idx < 2048; idx += 256) {
            const int kk = idx >> 5, nn = idx & 31;
            const int nl = nloc0 + nn;
            const int k  = k0 + kk;
            float v = 0.f;
            if (nl < HIDD) {
                if (seg == 0)      v = pw1[(long)k * HIDD + nl];
                else if (seg == 1) v = pw1[(long)(E3 + k) * HIDD + nl];
                else if (seg == 2) v = mw1[(long)k * HIDD + nl];
                else               v = pw1[(long)(2 * E3 + k) * HIDD + nl];
            }
            tile[kk][nn] = v;
        }
        __syncthreads();
        for (int idx = t; idx < 2048; idx += 256) {
            const int nn = idx >> 6, kk = idx & 63;
            u16 hi, lo; split2(tile[kk][nn], hi, lo);
            W12t_hi[(long)(n0 + nn) * E3 + k0 + kk] = hi;
            W12t_lo[(long)(n0 + nn) * E3 + k0 + kk] = lo;
        }
    } else if (bi < 1488) {
        const int k = bi - 720;
        if (t < 160) {
            float v = (t < HIDD) ? aw1[k * HIDD + t] : 0.f;
            u16 hi, lo; split2(v, hi, lo);
            AW1t_hi[(long)t * EDIM + k] = hi;
            AW1t_lo[(long)t * EDIM + k] = lo;
        }
    } else {
        const int r = bi - 1488;
        const int k = r % 160;
        const int which = r / 160;
        const float* src = (which == 0) ? aw2 : (which == 1) ? pw2 : mw2;
        u16* dh = (which == 0) ? AW2t_hi : (which == 1) ? PW2t_hi : MW2t_hi;
        u16* dl = (which == 0) ? AW2t_lo : (which == 1) ? PW2t_lo : MW2t_lo;
        if (t < 160) {
            float v = (t < HIDD && k < HIDD) ? src[k * HIDD + t] : 0.f;
            u16 hi, lo; split2(v, hi, lo);
            dh[t * 160 + k] = hi;
            dl[t * 160 + k] = lo;
        }
    }
}

// ---------------------------------------------------------------------------
// k_attn1: layer-1 K-split. Grid (48 rowblocks, 4 ksplit), 256 thr.
// ---------------------------------------------------------------------------
__global__ __launch_bounds__(256) void k_attn1(
    const float* __restrict__ X, const int* __restrict__ spans,
    const u16* __restrict__ AW1t_hi, const u16* __restrict__ AW1t_lo,
    float* __restrict__ AH1)
{
    __shared__ __align__(16) u16 As_hi[32 * 40];
    __shared__ __align__(16) u16 As_lo[32 * 40];
    __shared__ __align__(16) u16 Bs_hi[160 * 40];
    __shared__ __align__(16) u16 Bs_lo[160 * 40];

    const int t    = threadIdx.x;
    const int lane = t & 63;
    const int m    = lane & 15;
    const int quad = lane >> 4;
    const int w    = t >> 6;
    const int mt   = (w & 1) * 16;
    const int nb   = (w >> 1) * 80;
    const int ks   = blockIdx.y;

    const int rr = t >> 3, q = t & 7;
    const int grow = blockIdx.x * 32 + rr;
    const int bs = grow >> 3, sw = grow & 7;
    const int b  = bs / SS;
    const int tok = spans[bs] + sw;
    const float* arow = X + ((long)b * TT + tok) * EDIM;

    f32x4v acc[5];
    #pragma unroll
    for (int ht = 0; ht < 5; ++ht)
        #pragma unroll
        for (int r = 0; r < 4; ++r) acc[ht][r] = 0.f;

    for (int tt = 0; tt < 6; ++tt) {
        const int kk0 = ks * 192 + tt * 32;
        {
            const float4 xv = *(const float4*)&arow[kk0 + q * 4];
            ushort4 hv, lv;
            split2(xv.x, hv.x, lv.x); split2(xv.y, hv.y, lv.y);
            split2(xv.z, hv.z, lv.z); split2(xv.w, hv.w, lv.w);
            *(ushort4*)&As_hi[rr * 40 + q * 4] = hv;
            *(ushort4*)&As_lo[rr * 40 + q * 4] = lv;
        }
        #pragma unroll
        for (int it = 0; it < 3; ++it) {
            const int v = t + it * 256;
            if (v < 640) {
                const int h = v >> 2, qq = v & 3;
                *(uint4*)&Bs_hi[h * 40 + qq * 8] = *(const uint4*)&AW1t_hi[(long)h * EDIM + kk0 + qq * 8];
                *(uint4*)&Bs_lo[h * 40 + qq * 8] = *(const uint4*)&AW1t_lo[(long)h * EDIM + kk0 + qq * 8];
            }
        }
        __syncthreads();
        const frag ah = *(const frag*)&As_hi[(mt + m) * 40 + quad * 8];
        const frag al = *(const frag*)&As_lo[(mt + m) * 40 + quad * 8];
        #pragma unroll
        for (int ht = 0; ht < 5; ++ht) {
            const frag bh = *(const frag*)&Bs_hi[(nb + ht * 16 + m) * 40 + quad * 8];
            const frag bl = *(const frag*)&Bs_lo[(nb + ht * 16 + m) * 40 + quad * 8];
            acc[ht] = __builtin_amdgcn_mfma_f32_16x16x32_bf16(al, bh, acc[ht], 0, 0, 0);
            acc[ht] = __builtin_amdgcn_mfma_f32_16x16x32_bf16(ah, bl, acc[ht], 0, 0, 0);
            acc[ht] = __builtin_amdgcn_mfma_f32_16x16x32_bf16(ah, bh, acc[ht], 0, 0, 0);
        }
        __syncthreads();
    }
    #pragma unroll
    for (int ht = 0; ht < 5; ++ht) {
        #pragma unroll
        for (int r = 0; r < 4; ++r) {
            const int row = blockIdx.x * 32 + mt + quad * 4 + r;
            const int col = nb + ht * 16 + m;
            if (col < HIDD) atomicAdd(&AH1[row * 160 + col], acc[ht][r]);
        }
    }
}

// ---------------------------------------------------------------------------
// k_attn2: bias+relu on rows, layer2 MFMA, layer3 dot.
// GENERIC over [32-row blocks x 160] @ W2t[160x160] + w3 dot -> out[row].
// Used for attn (grid 48) AND mention (grid 6, with M/MW2t/mb*/mw3).
// ---------------------------------------------------------------------------
__global__ __launch_bounds__(256) void k_attn2(
    const float* __restrict__ AH1,
    const u16* __restrict__ AW2t_hi, const u16* __restrict__ AW2t_lo,
    const float* __restrict__ ab1, const float* __restrict__ ab2,
    const float* __restrict__ aw3, const float* __restrict__ ab3,
    float* __restrict__ attn_g)
{
    __shared__ __align__(16) u16 As_hi[32 * 40];
    __shared__ __align__(16) u16 As_lo[32 * 40];
    __shared__ __align__(16) u16 Bs_hi[160 * 40];
    __shared__ __align__(16) u16 Bs_lo[160 * 40];
    __shared__ float h1s[32 * 160];
    __shared__ float red[32];

    const int t    = threadIdx.x;
    const int lane = t & 63;
    const int m    = lane & 15;
    const int quad = lane >> 4;
    const int w    = t >> 6;
    const int mt   = (w & 1) * 16;
    const int nb   = (w >> 1) * 80;

    for (int u = t; u < 1280; u += 256) {
        const int row = u / 40, c4 = u - (u / 40) * 40;
        const int c0 = c4 * 4;
        const float4 v = *(const float4*)&AH1[(blockIdx.x * 32 + row) * 160 + c0];
        h1s[row * 160 + c0 + 0] = (c0 + 0 < HIDD) ? fmaxf(v.x + ab1[c0 + 0], 0.f) : 0.f;
        h1s[row * 160 + c0 + 1] = (c0 + 1 < HIDD) ? fmaxf(v.y + ab1[c0 + 1], 0.f) : 0.f;
        h1s[row * 160 + c0 + 2] = (c0 + 2 < HIDD) ? fmaxf(v.z + ab1[c0 + 2], 0.f) : 0.f;
        h1s[row * 160 + c0 + 3] = (c0 + 3 < HIDD) ? fmaxf(v.w + ab1[c0 + 3], 0.f) : 0.f;
    }
    if (t < 32) red[t] = 0.f;
    __syncthreads();

    const int rr = t >> 3, q = t & 7;
    f32x4v acc2[5];
    #pragma unroll
    for (int ht = 0; ht < 5; ++ht)
        #pragma unroll
        for (int r = 0; r < 4; ++r) acc2[ht][r] = 0.f;

    for (int kk = 0; kk < 5; ++kk) {
        {
            const float4 xv = *(const float4*)&h1s[rr * 160 + kk * 32 + q * 4];
            ushort4 hv, lv;
            split2(xv.x, hv.x, lv.x); split2(xv.y, hv.y, lv.y);
            split2(xv.z, hv.z, lv.z); split2(xv.w, hv.w, lv.w);
            *(ushort4*)&As_hi[rr * 40 + q * 4] = hv;
            *(ushort4*)&As_lo[rr * 40 + q * 4] = lv;
        }
        #pragma unroll
        for (int it = 0; it < 3; ++it) {
            const int v = t + it * 256;
            if (v < 640) {
                const int h = v >> 2, qq = v & 3;
                *(uint4*)&Bs_hi[h * 40 + qq * 8] = *(const uint4*)&AW2t_hi[h * 160 + kk * 32 + qq * 8];
                *(uint4*)&Bs_lo[h * 40 + qq * 8] = *(const uint4*)&AW2t_lo[h * 160 + kk * 32 + qq * 8];
            }
        }
        __syncthreads();
        const frag ah = *(const frag*)&As_hi[(mt + m) * 40 + quad * 8];
        const frag al = *(const frag*)&As_lo[(mt + m) * 40 + quad * 8];
        #pragma unroll
        for (int ht = 0; ht < 5; ++ht) {
            const frag bh = *(const frag*)&Bs_hi[(nb + ht * 16 + m) * 40 + quad * 8];
            const frag bl = *(const frag*)&Bs_lo[(nb + ht * 16 + m) * 40 + quad * 8];
            acc2[ht] = __builtin_amdgcn_mfma_f32_16x16x32_bf16(al, bh, acc2[ht], 0, 0, 0);
            acc2[ht] = __builtin_amdgcn_mfma_f32_16x16x32_bf16(ah, bl, acc2[ht], 0, 0, 0);
            acc2[ht] = __builtin_amdgcn_mfma_f32_16x16x32_bf16(ah, bh, acc2[ht], 0, 0, 0);
        }
        __syncthreads();
    }

    float s[4] = {0.f, 0.f, 0.f, 0.f};
    #pragma unroll
    for (int ht = 0; ht < 5; ++ht) {
        const int col = nb + ht * 16 + m;
        if (col < HIDD) {
            const float w3 = aw3[col];
            #pragma unroll
            for (int r = 0; r < 4; ++r)
                s[r] += fmaxf(acc2[ht][r] + ab2[col], 0.f) * w3;
        }
    }
    #pragma unroll
    for (int r = 0; r < 4; ++r) {
        for (int off = 8; off > 0; off >>= 1) s[r] += __shfl_down(s[r], off, 16);
    }
    if (m == 0) {
        #pragma unroll
        for (int r = 0; r < 4; ++r) atomicAdd(&red[mt + quad * 4 + r], s[r]);
    }
    __syncthreads();
    if (t < 32) attn_g[blockIdx.x * 32 + t] = red[t] + ab3[0];
}

// ---------------------------------------------------------------------------
// k_span_g: build g_i fp32 (G_ws) AND bf16 hi/lo split (Gs_hi/lo). 192 blocks.
// ---------------------------------------------------------------------------
__global__ __launch_bounds__(256) void k_span_g(
    const float* __restrict__ X, const int* __restrict__ spans,
    const float* __restrict__ attn_g, float* __restrict__ G_ws,
    u16* __restrict__ Gs_hi, u16* __restrict__ Gs_lo)
{
    __shared__ float a8[8];
    const int t  = threadIdx.x;
    const int bs = blockIdx.x;
    const int b  = bs / SS;
    const int start = spans[bs];
    const float* xb = X + ((long)b * TT + start) * EDIM;
    float* Gp = G_ws + (long)bs * E3;
    u16* Gh = Gs_hi + (long)bs * E3;
    u16* Gl = Gs_lo + (long)bs * E3;
    if (t < 8) a8[t] = attn_g[bs * 8 + t];
    __syncthreads();

    for (int e = t; e < EDIM; e += 256) {
        const float gs = xb[e];
        const float ge = xb[7 * EDIM + e];
        float ga = 0.f;
        #pragma unroll
        for (int w = 0; w < 8; ++w) ga += xb[w * EDIM + e] * a8[w];
        Gp[e] = gs; Gp[EDIM + e] = ge; Gp[2 * EDIM + e] = ga;
        u16 hi, lo;
        split2(gs, hi, lo); Gh[e] = hi;            Gl[e] = lo;
        split2(ge, hi, lo); Gh[EDIM + e] = hi;     Gl[EDIM + e] = lo;
        split2(ga, hi, lo); Gh[2 * EDIM + e] = hi; Gl[2 * EDIM + e] = lo;
    }
}

// ---------------------------------------------------------------------------
// k_heavy: FUSED pairmm + uvm (both depend only on span_g + prep).
// 1-D grid of 684 blocks:
//   [0,576): pairmm — ks=id%3, i=(id/3)%96, b=id/288. r11 code verbatim.
//   [576,684): uvm — mb=u%3, nb=(u/3)%3, kz=u/9.
// LDS: 48128-byte union (pairmm layout / uvm layout).
// ---------------------------------------------------------------------------
__global__ __launch_bounds__(256) void k_heavy(
    const float* __restrict__ G_ws,
    const u16* __restrict__ Gs_hi, const u16* __restrict__ Gs_lo,
    const u16* __restrict__ W12t_hi, const u16* __restrict__ W12t_lo,
    const u16* __restrict__ PCt_hi, const u16* __restrict__ PCt_lo,
    float* __restrict__ H1parts, float* __restrict__ UVM)
{
    __shared__ __align__(16) char smem[48128];
    const int id = blockIdx.x;
    const int t  = threadIdx.x;
    const int lane = t & 63;
    const int m    = lane & 15;
    const int quad = lane >> 4;
    const int w    = t >> 6;

    if (id < 576) {
        // ======================= pairmm (r11, 57 µs) =======================
        float* gis  = (float*)smem;                        // 768 f
        float* gjst = (float*)(smem + 3072);               // 96*32 f
        u16* As_hi  = (u16*)(smem + 15360);                // 96*32
        u16* As_lo  = (u16*)(smem + 21504);
        u16* Bs_hi  = (u16*)(smem + 27648);                // 160*32
        u16* Bs_lo  = (u16*)(smem + 37888);

        const int ks = id % 3;
        const int i  = (id / 3) % SS;
        const int b  = id / 288;
        const int ksbase = ks * 768;
        const int jt0 = i >> 4;
        const int ntiles = 6 - jt0;
        const int j0 = jt0 * 16;
        const int R  = 96 - j0;
        const int nI = R >> 3;

        const int hb   = (w & 1) * 80;
        const int apar = w >> 1;
        const int Bl_h = lane >> 2;
        const int Bl_c = lane & 3;
        const int gj_r = lane >> 3;
        const int gj_c = lane & 7;

        const float* Gi = G_ws + (long)(b * SS + i) * E3 + ksbase;
        for (int e = t; e < 768; e += 256) gis[e] = Gi[e];

        f32x4v acc[3][5];
        #pragma unroll
        for (int jt = 0; jt < 3; ++jt)
            #pragma unroll
            for (int ht = 0; ht < 5; ++ht)
                #pragma unroll
                for (int r = 0; r < 4; ++r) acc[jt][ht][r] = 0.f;

        for (int tt = 0; tt < 24; ++tt) {
            const int kk0 = ksbase + tt * 32;
            for (int q2 = w; q2 < 10; q2 += 4) {
                const int h  = q2 * 16 + Bl_h;
                const int qd = (Bl_c - (h >> 1)) & 3;
                const long so = (long)h * E3 + kk0 + qd * 8;
                async16(&PCt_hi[so], &Bs_hi[q2 * 512]);
                async16(&PCt_lo[so], &Bs_lo[q2 * 512]);
            }
            for (int g2 = w; g2 < nI; g2 += 4) {
                const int row = j0 + g2 * 8 + gj_r;
                async16(&G_ws[(long)(b * SS + row) * E3 + kk0 + gj_c * 4],
                        &gjst[g2 * 256]);
            }
            __syncthreads();

            for (int u = t; u < R * 4; u += 256) {
                const int rr = u >> 2, qd = u & 3;
                const float4 g0 = *(const float4*)&gjst[rr * 32 + qd * 8];
                const float4 g1 = *(const float4*)&gjst[rr * 32 + qd * 8 + 4];
                const int kl = tt * 32 + qd * 8;
                u16x8 hv, lv; u16 h, l;
                split2(g0.x * gis[kl + 0], h, l); hv[0] = h; lv[0] = l;
                split2(g0.y * gis[kl + 1], h, l); hv[1] = h; lv[1] = l;
                split2(g0.z * gis[kl + 2], h, l); hv[2] = h; lv[2] = l;
                split2(g0.w * gis[kl + 3], h, l); hv[3] = h; lv[3] = l;
                split2(g1.x * gis[kl + 4], h, l); hv[4] = h; lv[4] = l;
                split2(g1.y * gis[kl + 5], h, l); hv[5] = h; lv[5] = l;
                split2(g1.z * gis[kl + 6], h, l); hv[6] = h; lv[6] = l;
                split2(g1.w * gis[kl + 7], h, l); hv[7] = h; lv[7] = l;
                const int o = swzoff(rr, qd);
                *(u16x8*)&As_hi[o] = hv;
                *(u16x8*)&As_lo[o] = lv;
            }
            __syncthreads();

            frag ah[3], al[3];
            #pragma unroll
            for (int u = 0; u < 3; ++u) {
                const int a = apar + 2 * u;
                if (a < ntiles) {
                    const int o = swzoff(a * 16 + m, quad);
                    ah[u] = *(const frag*)&As_hi[o];
                    al[u] = *(const frag*)&As_lo[o];
                }
            }
            #pragma unroll
            for (int ht = 0; ht < 5; ++ht) {
                const int o = swzoff(hb + ht * 16 + m, quad);
                const frag bh = *(const frag*)&Bs_hi[o];
                const frag bl = *(const frag*)&Bs_lo[o];
                #pragma unroll
                for (int u = 0; u < 3; ++u) {
                    if (apar + 2 * u < ntiles) {
                        acc[u][ht] = __builtin_amdgcn_mfma_f32_16x16x32_bf16(al[u], bh, acc[u][ht], 0, 0, 0);
                        acc[u][ht] = __builtin_amdgcn_mfma_f32_16x16x32_bf16(ah[u], bl, acc[u][ht], 0, 0, 0);
                        acc[u][ht] = __builtin_amdgcn_mfma_f32_16x16x32_bf16(ah[u], bh, acc[u][ht], 0, 0, 0);
                    }
                }
            }
            __syncthreads();
        }

        float* dst = H1parts + (long)ks * ((long)BB * SS * SS * 160);
        #pragma unroll
        for (int u = 0; u < 3; ++u) {
            const int a = apar + 2 * u;
            if (a < ntiles) {
                #pragma unroll
                for (int ht = 0; ht < 5; ++ht) {
                    #pragma unroll
                    for (int r = 0; r < 4; ++r) {
                        const int j = (jt0 + a) * 16 + quad * 4 + r;
                        const int h = hb + ht * 16 + m;
                        dst[((long)(b * SS + i) * SS + j) * 160 + h] = acc[u][ht][r];
                    }
                }
            }
        }
    } else {
        // ========================== uvm (108 blocks) =======================
        u16* As_hi = (u16*)smem;                           // 64*40
        u16* As_lo = (u16*)(smem + 5120);
        u16* Bs_hi = (u16*)(smem + 10240);                 // 160*40
        u16* Bs_lo = (u16*)(smem + 23040);

        const int u0 = id - 576;
        const int mb = u0 % 3;
        const int nb = (u0 / 3) % 3;
        const int kz = u0 / 9;
        const int mhalf = (w & 1) * 32;
        const int nbase = (w >> 1) * 80;
        const int arr = t >> 2, aq = t & 3;

        f32x4v acc[2][5];
        #pragma unroll
        for (int i = 0; i < 2; ++i)
            #pragma unroll
            for (int j = 0; j < 5; ++j)
                #pragma unroll
                for (int r = 0; r < 4; ++r) acc[i][j][r] = 0.f;

        for (int tt = 0; tt < 6; ++tt) {
            const int kk0 = kz * 192 + tt * 32;
            *(uint4*)&As_hi[arr * 40 + aq * 8] = *(const uint4*)&Gs_hi[(long)(mb * 64 + arr) * E3 + kk0 + aq * 8];
            *(uint4*)&As_lo[arr * 40 + aq * 8] = *(const uint4*)&Gs_lo[(long)(mb * 64 + arr) * E3 + kk0 + aq * 8];
            #pragma unroll
            for (int it = 0; it < 3; ++it) {
                const int v = t + it * 256;
                if (v < 640) {
                    const int h = v >> 2, qq = v & 3;
                    *(uint4*)&Bs_hi[h * 40 + qq * 8] = *(const uint4*)&W12t_hi[(long)(nb * 160 + h) * E3 + kk0 + qq * 8];
                    *(uint4*)&Bs_lo[h * 40 + qq * 8] = *(const uint4*)&W12t_lo[(long)(nb * 160 + h) * E3 + kk0 + qq * 8];
                }
            }
            __syncthreads();
            frag ah[2], al[2];
            #pragma unroll
            for (int mt = 0; mt < 2; ++mt) {
                ah[mt] = *(const frag*)&As_hi[(mhalf + mt * 16 + m) * 40 + quad * 8];
                al[mt] = *(const frag*)&As_lo[(mhalf + mt * 16 + m) * 40 + quad * 8];
            }
            #pragma unroll
            for (int ht = 0; ht < 5; ++ht) {
                const frag bh = *(const frag*)&Bs_hi[(nbase + ht * 16 + m) * 40 + quad * 8];
                const frag bl = *(const frag*)&Bs_lo[(nbase + ht * 16 + m) * 40 + quad * 8];
                #pragma unroll
                for (int mt = 0; mt < 2; ++mt) {
                    acc[mt][ht] = __builtin_amdgcn_mfma_f32_16x16x32_bf16(al[mt], bh, acc[mt][ht], 0, 0, 0);
                    acc[mt][ht] = __builtin_amdgcn_mfma_f32_16x16x32_bf16(ah[mt], bl, acc[mt][ht], 0, 0, 0);
                    acc[mt][ht] = __builtin_amdgcn_mfma_f32_16x16x32_bf16(ah[mt], bh, acc[mt][ht], 0, 0, 0);
                }
            }
            __syncthreads();
        }
        float* dst = UVM + (long)nb * (192 * 160);
        #pragma unroll
        for (int mt = 0; mt < 2; ++mt) {
            #pragma unroll
            for (int ht = 0; ht < 5; ++ht) {
                #pragma unroll
                for (int r = 0; r < 4; ++r) {
                    const int row = mb * 64 + mhalf + mt * 16 + quad * 4 + r;
                    const int c   = nbase + ht * 16 + m;
                    atomicAdd(&dst[row * 160 + c], acc[mt][ht][r]);
                }
            }
        }
    }
}

// ---------------------------------------------------------------------------
// k_pair2: MFMA finish, 3-way j-split. Grid (3 js, 192 bi), 256 thr.
// Block handles j in [js*32, js*32+32); LDS ~48 KB -> 3 blocks/CU.
// ---------------------------------------------------------------------------
__global__ __launch_bounds__(256) void k_pair2(
    const float* __restrict__ H1parts,
    const float* __restrict__ U_ws, const float* __restrict__ V_ws,
    const float* __restrict__ pb1, const float* __restrict__ m_ws,
    const u16* __restrict__ PW2t_hi, const u16* __restrict__ PW2t_lo,
    const float* __restrict__ pb2, const float* __restrict__ pw3,
    const float* __restrict__ pb3,
    float* __restrict__ out)
{
    __shared__ __align__(16) u16 As_hi[32 * 168];
    __shared__ __align__(16) u16 As_lo[32 * 168];
    __shared__ __align__(16) u16 Bs_hi[160 * 40];
    __shared__ __align__(16) u16 Bs_lo[160 * 40];
    __shared__ float uv[160];
    __shared__ float red[32];

    const long partsz = (long)BB * SS * SS * 160;
    const int t  = threadIdx.x;
    const int js = blockIdx.x;
    const int bi = blockIdx.y;          // b*96 + i
    const int b  = bi / SS;
    const int ii = bi - b * SS;
    const int jb0 = js * 32;

    if (t < 160) uv[t] = U_ws[bi * 160 + t] + ((t < HIDD) ? pb1[t] : 0.f);
    if (t < 32) red[t] = 0.f;
    __syncthreads();

    // phase 1: gather 32 rows of h1 = relu(sum parts + U + V + pb1), split
    for (int u = t; u < 32 * 40; u += 256) {
        const int jl = u / 40, hq = u - (u / 40) * 40;
        const int j  = jb0 + jl;
        const int h0 = hq * 4;
        const int mn = ii < j ? ii : j;
        const int mx = ii < j ? j : ii;
        const long idx = (((long)b * SS + mn) * SS + mx) * 160 + h0;
        const float4 vv = *(const float4*)&V_ws[(b * SS + j) * 160 + h0];
        const float4 a0 = *(const float4*)&H1parts[idx];
        const float4 a1 = *(const float4*)&H1parts[partsz + idx];
        const float4 a2 = *(const float4*)&H1parts[2 * partsz + idx];
        const float p0 = fmaxf(a0.x + a1.x + a2.x + vv.x + uv[h0 + 0], 0.f);
        const float p1 = fmaxf(a0.y + a1.y + a2.y + vv.y + uv[h0 + 1], 0.f);
        const float p2 = fmaxf(a0.z + a1.z + a2.z + vv.z + uv[h0 + 2], 0.f);
        const float p3 = fmaxf(a0.w + a1.w + a2.w + vv.w + uv[h0 + 3], 0.f);
        ushort4 hv, lv;
        split2(p0, hv.x, lv.x); split2(p1, hv.y, lv.y);
        split2(p2, hv.z, lv.z); split2(p3, hv.w, lv.w);
        *(ushort4*)&As_hi[jl * 168 + h0] = hv;
        *(ushort4*)&As_lo[jl * 168 + h0] = lv;
    }
    __syncthreads();

    // phase 2: layer2 MFMA [32x160]@[160x160]
    const int lane = t & 63;
    const int m    = lane & 15;
    const int quad = lane >> 4;
    const int w    = t >> 6;
    const int jt   = w >> 1;           // j-tile 0..1 (16 rows each)
    const int nbs  = (w & 1) * 80;     // 5 n-tiles

    f32x4v acc[5];
    #pragma unroll
    for (int ht = 0; ht < 5; ++ht)
        #pragma unroll
        for (int r = 0; r < 4; ++r) acc[ht][r] = 0.f;

    for (int kk = 0; kk < 5; ++kk) {
        #pragma unroll
        for (int it = 0; it < 3; ++it) {
            const int v = t + it * 256;
            if (v < 640) {
                const int n = v >> 2, qq = v & 3;
                *(uint4*)&Bs_hi[n * 40 + qq * 8] = *(const uint4*)&PW2t_hi[n * 160 + kk * 32 + qq * 8];
                *(uint4*)&Bs_lo[n * 40 + qq * 8] = *(const uint4*)&PW2t_lo[n * 160 + kk * 32 + qq * 8];
            }
        }
        __syncthreads();
        const frag ah = *(const frag*)&As_hi[(jt * 16 + m) * 168 + kk * 32 + quad * 8];
        const frag al = *(const frag*)&As_lo[(jt * 16 + m) * 168 + kk * 32 + quad * 8];
        #pragma unroll
        for (int ht = 0; ht < 5; ++ht) {
            const frag bh = *(const frag*)&Bs_hi[(nbs + ht * 16 + m) * 40 + quad * 8];
            const frag bl = *(const frag*)&Bs_lo[(nbs + ht * 16 + m) * 40 + quad * 8];
            acc[ht] = __builtin_amdgcn_mfma_f32_16x16x32_bf16(al, bh, acc[ht], 0, 0, 0);
            acc[ht] = __builtin_amdgcn_mfma_f32_16x16x32_bf16(ah, bl, acc[ht], 0, 0, 0);
            acc[ht] = __builtin_amdgcn_mfma_f32_16x16x32_bf16(ah, bh, acc[ht], 0, 0, 0);
        }
        __syncthreads();
    }

    // phase 3: layer3 dot + reduce
    float s[4] = {0.f, 0.f, 0.f, 0.f};
    #pragma unroll
    for (int ht = 0; ht < 5; ++ht) {
        const int col = nbs + ht * 16 + m;
        if (col < HIDD) {
            const float w3 = pw3[col];
            const float b2 = pb2[col];
            #pragma unroll
            for (int r = 0; r < 4; ++r)
                s[r] += fmaxf(acc[ht][r] + b2, 0.f) * w3;
        }
    }
    #pragma unroll
    for (int r = 0; r < 4; ++r)
        for (int off = 8; off > 0; off >>= 1)
            s[r] += __shfl_down(s[r], off, 16);
    if (m == 0) {
        #pragma unroll
        for (int r = 0; r < 4; ++r)
            atomicAdd(&red[jt * 16 + quad * 4 + r], s[r]);
    }
    __syncthreads();

    if (t < 32) {
        const int j = jb0 + t;
        const float sc = red[t] + pb3[0];
        const float v = (m_ws[bi] + m_ws[b * SS + j] + sc) * (1.f / 3.f);
        out[(long)bi * SS + j] = fminf(fmaxf(v, 0.f), 1.f);
    }
}

// ---------------------------------------------------------------------------
extern "C" void kernel_launch(void* const* d_in, const int* in_sizes, int n_in,
                              void* d_out, int out_size, void* d_ws, size_t ws_size,
                              hipStream_t stream)
{
    const float* X     = (const float*)d_in[0];
    const int*   spans = (const int*)  d_in[1];
    const float* aw1 = (const float*)d_in[2];
    const float* ab1 = (const float*)d_in[3];
    const float* aw2 = (const float*)d_in[4];
    const float* ab2 = (const float*)d_in[5];
    const float* aw3 = (const float*)d_in[6];
    const float* ab3 = (const float*)d_in[7];
    const float* mw1 = (const float*)d_in[8];
    const float* mb1 = (const float*)d_in[9];
    const float* mw2 = (const float*)d_in[10];
    const float* mb2 = (const float*)d_in[11];
    const float* mw3 = (const float*)d_in[12];
    const float* mb3 = (const float*)d_in[13];
    const float* pw1 = (const float*)d_in[14];
    const float* pb1 = (const float*)d_in[15];
    const float* pw2 = (const float*)d_in[16];
    const float* pb2 = (const float*)d_in[17];
    const float* pw3 = (const float*)d_in[18];
    const float* pb3 = (const float*)d_in[19];
    float* out = (float*)d_out;

    char* p = (char*)d_ws;
    float* attn_g  = (float*)p;  p += 6144;                       // 1536 f
    float* G_ws    = (float*)p;  p += (long)442368 * 4;           // 192x2304 f
    u16*   Gs_hi   = (u16*)p;    p += (long)442368 * 2;
    u16*   Gs_lo   = (u16*)p;    p += (long)442368 * 2;
    float* UVM     = (float*)p;  p += (long)3 * 192 * 160 * 4;    // U|V|M (zeroed)
    float* AH1     = (float*)p;  p += (long)1536 * 160 * 4;       // attn L1 partials (zeroed)
    float* m_ws    = (float*)p;  p += 1024;
    u16*   W12t_hi = (u16*)p;    p += (long)640 * E3 * 2;         // PA|PB|mw1|PC
    u16*   W12t_lo = (u16*)p;    p += (long)640 * E3 * 2;
    u16*   AW1t_hi = (u16*)p;    p += (long)160 * EDIM * 2;
    u16*   AW1t_lo = (u16*)p;    p += (long)160 * EDIM * 2;
    u16*   AW2t_hi = (u16*)p;    p += 160 * 160 * 2;
    u16*   AW2t_lo = (u16*)p;    p += 160 * 160 * 2;
    u16*   PW2t_hi = (u16*)p;    p += 160 * 160 * 2;
    u16*   PW2t_lo = (u16*)p;    p += 160 * 160 * 2;
    u16*   MW2t_hi = (u16*)p;    p += 160 * 160 * 2;
    u16*   MW2t_lo = (u16*)p;    p += 160 * 160 * 2;
    float* H1parts = (float*)p;   // 3 * 11.8 MB

    float* U_ws = UVM;
    float* V_ws = UVM + 192 * 160;
    float* M_ws = UVM + 2 * 192 * 160;
    const u16* PCt_hi = W12t_hi + (long)480 * E3;
    const u16* PCt_lo = W12t_lo + (long)480 * E3;

    // zero UVM + AH1 (contiguous atomic targets)
    hipMemsetAsync(UVM, 0, ((size_t)3 * 192 * 160 + (size_t)1536 * 160) * sizeof(float), stream);

    k_prep_all<<<dim3(1968), 256, 0, stream>>>(pw1, mw1, aw1, aw2, pw2, mw2,
                                               W12t_hi, W12t_lo, AW1t_hi, AW1t_lo,
                                               AW2t_hi, AW2t_lo, PW2t_hi, PW2t_lo,
                                               MW2t_hi, MW2t_lo);

    k_attn1<<<dim3(48, 4), 256, 0, stream>>>(X, spans, AW1t_hi, AW1t_lo, AH1);
    k_attn2<<<dim3(48), 256, 0, stream>>>(AH1, AW2t_hi, AW2t_lo, ab1, ab2, aw3, ab3, attn_g);
    k_span_g<<<dim3(BB * SS), 256, 0, stream>>>(X, spans, attn_g, G_ws, Gs_hi, Gs_lo);

    // fused pairmm (576 blocks) + uvm (108 blocks)
    k_heavy<<<dim3(684), 256, 0, stream>>>(G_ws, Gs_hi, Gs_lo, W12t_hi, W12t_lo,
                                           PCt_hi, PCt_lo, H1parts, UVM);

    // mention layers 2-3: identical shape to attn2 -> reuse kernel (grid 6)
    k_attn2<<<dim3(6), 256, 0, stream>>>(M_ws, MW2t_hi, MW2t_lo, mb1, mb2, mw3, mb3, m_ws);

    k_pair2<<<dim3(3, BB * SS), 256, 0, stream>>>(
        H1parts, U_ws, V_ws, pb1, m_ws, PW2t_hi, PW2t_lo, pb2, pw3, pb3, out);
}

// Round 14
// 213.867 us; speedup vs baseline: 1.2140x; 1.0079x over previous
//
#include <hip/hip_runtime.h>

// Problem constants
#define EDIM   768
#define E3     2304
#define HIDD   150
#define TT     2048
#define SS     96
#define BB     2

typedef unsigned short u16;
using frag   = __attribute__((ext_vector_type(8))) short;   // 8 bf16 = 4 VGPR
using f32x4v = __attribute__((ext_vector_type(4))) float;   // 4 fp32 acc
using u16x8  = __attribute__((ext_vector_type(8))) unsigned short;

__device__ __forceinline__ u16 bf16rn(float f) {
    union { float f; unsigned u; } v; v.f = f;
    unsigned r = v.u + 0x7FFF + ((v.u >> 16) & 1);
    return (u16)(r >> 16);
}
__device__ __forceinline__ float bf16tof(u16 h) {
    union { unsigned u; float f; } v; v.u = ((unsigned)h) << 16;
    return v.f;
}
__device__ __forceinline__ void split2(float f, u16& hi, u16& lo) {
    hi = bf16rn(f); lo = bf16rn(f - bf16tof(hi));
}
// pairmm LDS swizzle: chunk (row, qd) -> u16 offset. Zero conflicts (r7-measured).
__device__ __forceinline__ int swzoff(int row, int qd) {
    return row * 32 + (((qd + (row >> 1)) & 3) << 3);
}
// async 16B global->LDS copy (per-lane src, dest = uniform base + lane*16)
__device__ __forceinline__ void async16(const void* g, void* l) {
    __builtin_amdgcn_global_load_lds(
        (const __attribute__((address_space(1))) void*)g,
        (__attribute__((address_space(3))) void*)l, 16, 0, 0);
}

// ---------------------------------------------------------------------------
// k_prep_aw1: AW1t[n][k] bf16 hi/lo, n in [0,160), k in [0,768). Grid 768.
// Only prep that gates attn1 -- runs alone first; the rest rides with attn1.
// ---------------------------------------------------------------------------
__global__ __launch_bounds__(256) void k_prep_aw1(
    const float* __restrict__ aw1, u16* __restrict__ W_hi, u16* __restrict__ W_lo)
{
    const int k = blockIdx.x, t = threadIdx.x;
    if (t < 160) {
        float v = (t < HIDD) ? aw1[k * HIDD + t] : 0.f;
        u16 hi, lo; split2(v, hi, lo);
        W_hi[(long)t * EDIM + k] = hi;
        W_lo[(long)t * EDIM + k] = lo;
    }
}

// ---------------------------------------------------------------------------
// k_fused1: attn layer-1 (288 blocks) + remaining weight prep (1200 blocks).
// blocks [0,288):     attn1, rb = id%48, ks = id/48 (6 k-splits x 4 chunks)
// blocks [288,1008):  W12t transpose (bi' = id-288: kb = bi'%36, nb = bi'/36)
// blocks [1008,1488): AW2t (0) / PW2t (1) / MW2t (2), k = (id-1008)%160
// ---------------------------------------------------------------------------
__global__ __launch_bounds__(256) void k_fused1(
    const float* __restrict__ X, const int* __restrict__ spans,
    const u16* __restrict__ AW1t_hi, const u16* __restrict__ AW1t_lo,
    float* __restrict__ AH1,
    const float* __restrict__ pw1, const float* __restrict__ mw1,
    const float* __restrict__ aw2, const float* __restrict__ pw2,
    const float* __restrict__ mw2,
    u16* __restrict__ W12t_hi, u16* __restrict__ W12t_lo,
    u16* __restrict__ AW2t_hi, u16* __restrict__ AW2t_lo,
    u16* __restrict__ PW2t_hi, u16* __restrict__ PW2t_lo,
    u16* __restrict__ MW2t_hi, u16* __restrict__ MW2t_lo)
{
    __shared__ __align__(16) char smem[32768];
    const int id = blockIdx.x;
    const int t  = threadIdx.x;

    if (id < 288) {
        // ============================ attn1 ==============================
        u16* As_hi = (u16*)smem;                 // 32*40
        u16* As_lo = (u16*)(smem + 2560);
        u16* Bs_hi = (u16*)(smem + 5120);        // 160*40
        u16* Bs_lo = (u16*)(smem + 17920);

        const int lane = t & 63;
        const int m    = lane & 15;
        const int quad = lane >> 4;
        const int w    = t >> 6;
        const int mt   = (w & 1) * 16;
        const int nb   = (w >> 1) * 80;
        const int rb   = id % 48;
        const int ks   = id / 48;

        const int rr = t >> 3, q = t & 7;
        const int grow = rb * 32 + rr;
        const int bs = grow >> 3, sw = grow & 7;
        const int b  = bs / SS;
        const int tok = spans[bs] + sw;
        const float* arow = X + ((long)b * TT + tok) * EDIM;

        f32x4v acc[5];
        #pragma unroll
        for (int ht = 0; ht < 5; ++ht)
            #pragma unroll
            for (int r = 0; r < 4; ++r) acc[ht][r] = 0.f;

        for (int tt = 0; tt < 4; ++tt) {
            const int kk0 = ks * 128 + tt * 32;
            {
                const float4 xv = *(const float4*)&arow[kk0 + q * 4];
                ushort4 hv, lv;
                split2(xv.x, hv.x, lv.x); split2(xv.y, hv.y, lv.y);
                split2(xv.z, hv.z, lv.z); split2(xv.w, hv.w, lv.w);
                *(ushort4*)&As_hi[rr * 40 + q * 4] = hv;
                *(ushort4*)&As_lo[rr * 40 + q * 4] = lv;
            }
            #pragma unroll
            for (int it = 0; it < 3; ++it) {
                const int v = t + it * 256;
                if (v < 640) {
                    const int h = v >> 2, qq = v & 3;
                    *(uint4*)&Bs_hi[h * 40 + qq * 8] = *(const uint4*)&AW1t_hi[(long)h * EDIM + kk0 + qq * 8];
                    *(uint4*)&Bs_lo[h * 40 + qq * 8] = *(const uint4*)&AW1t_lo[(long)h * EDIM + kk0 + qq * 8];
                }
            }
            __syncthreads();
            const frag ah = *(const frag*)&As_hi[(mt + m) * 40 + quad * 8];
            const frag al = *(const frag*)&As_lo[(mt + m) * 40 + quad * 8];
            #pragma unroll
            for (int ht = 0; ht < 5; ++ht) {
                const frag bh = *(const frag*)&Bs_hi[(nb + ht * 16 + m) * 40 + quad * 8];
                const frag bl = *(const frag*)&Bs_lo[(nb + ht * 16 + m) * 40 + quad * 8];
                acc[ht] = __builtin_amdgcn_mfma_f32_16x16x32_bf16(al, bh, acc[ht], 0, 0, 0);
                acc[ht] = __builtin_amdgcn_mfma_f32_16x16x32_bf16(ah, bl, acc[ht], 0, 0, 0);
                acc[ht] = __builtin_amdgcn_mfma_f32_16x16x32_bf16(ah, bh, acc[ht], 0, 0, 0);
            }
            __syncthreads();
        }
        #pragma unroll
        for (int ht = 0; ht < 5; ++ht) {
            #pragma unroll
            for (int r = 0; r < 4; ++r) {
                const int row = rb * 32 + mt + quad * 4 + r;
                const int col = nb + ht * 16 + m;
                if (col < HIDD) atomicAdd(&AH1[row * 160 + col], acc[ht][r]);
            }
        }
    } else if (id < 1008) {
        // ====================== W12t transpose ===========================
        float (*tile)[33] = (float(*)[33])smem;  // 64*33 f = 8448 B
        const int bi = id - 288;
        const int k0 = (bi % 36) * 64;
        const int n0 = (bi / 36) * 32;
        const int seg = n0 / 160;
        const int nloc0 = n0 - seg * 160;
        for (int idx = t; idx < 2048; idx += 256) {
            const int kk = idx >> 5, nn = idx & 31;
            const int nl = nloc0 + nn;
            const int k  = k0 + kk;
            float v = 0.f;
            if (nl < HIDD) {
                if (seg == 0)      v = pw1[(long)k * HIDD + nl];
                else if (seg == 1) v = pw1[(long)(E3 + k) * HIDD + nl];
                else if (seg == 2) v = mw1[(long)k * HIDD + nl];
                else               v = pw1[(long)(2 * E3 + k) * HIDD + nl];
            }
            tile[kk][nn] = v;
        }
        __syncthreads();
        for (int idx = t; idx < 2048; idx += 256) {
            const int nn = idx >> 6, kk = idx & 63;
            u16 hi, lo; split2(tile[kk][nn], hi, lo);
            W12t_hi[(long)(n0 + nn) * E3 + k0 + kk] = hi;
            W12t_lo[(long)(n0 + nn) * E3 + k0 + kk] = lo;
        }
    } else {
        // ===================== square-weight preps =======================
        const int r = id - 1008;
        const int k = r % 160;
        const int which = r / 160;
        const float* src = (which == 0) ? aw2 : (which == 1) ? pw2 : mw2;
        u16* dh = (which == 0) ? AW2t_hi : (which == 1) ? PW2t_hi : MW2t_hi;
        u16* dl = (which == 0) ? AW2t_lo : (which == 1) ? PW2t_lo : MW2t_lo;
        if (t < 160) {
            float v = (t < HIDD && k < HIDD) ? src[k * HIDD + t] : 0.f;
            u16 hi, lo; split2(v, hi, lo);
            dh[t * 160 + k] = hi;
            dl[t * 160 + k] = lo;
        }
    }
}

// ---------------------------------------------------------------------------
// k_attn2: bias+relu on rows, layer2 MFMA, layer3 dot.
// GENERIC over [32-row blocks x 160] @ W2t[160x160] + w3 dot -> out[row].
// Used for attn (grid 48) AND mention (grid 6, with M/MW2t/mb*/mw3).
// ---------------------------------------------------------------------------
__global__ __launch_bounds__(256) void k_attn2(
    const float* __restrict__ AH1,
    const u16* __restrict__ AW2t_hi, const u16* __restrict__ AW2t_lo,
    const float* __restrict__ ab1, const float* __restrict__ ab2,
    const float* __restrict__ aw3, const float* __restrict__ ab3,
    float* __restrict__ attn_g)
{
    __shared__ __align__(16) u16 As_hi[32 * 40];
    __shared__ __align__(16) u16 As_lo[32 * 40];
    __shared__ __align__(16) u16 Bs_hi[160 * 40];
    __shared__ __align__(16) u16 Bs_lo[160 * 40];
    __shared__ float h1s[32 * 160];
    __shared__ float red[32];

    const int t    = threadIdx.x;
    const int lane = t & 63;
    const int m    = lane & 15;
    const int quad = lane >> 4;
    const int w    = t >> 6;
    const int mt   = (w & 1) * 16;
    const int nb   = (w >> 1) * 80;

    for (int u = t; u < 1280; u += 256) {
        const int row = u / 40, c4 = u - (u / 40) * 40;
        const int c0 = c4 * 4;
        const float4 v = *(const float4*)&AH1[(blockIdx.x * 32 + row) * 160 + c0];
        h1s[row * 160 + c0 + 0] = (c0 + 0 < HIDD) ? fmaxf(v.x + ab1[c0 + 0], 0.f) : 0.f;
        h1s[row * 160 + c0 + 1] = (c0 + 1 < HIDD) ? fmaxf(v.y + ab1[c0 + 1], 0.f) : 0.f;
        h1s[row * 160 + c0 + 2] = (c0 + 2 < HIDD) ? fmaxf(v.z + ab1[c0 + 2], 0.f) : 0.f;
        h1s[row * 160 + c0 + 3] = (c0 + 3 < HIDD) ? fmaxf(v.w + ab1[c0 + 3], 0.f) : 0.f;
    }
    if (t < 32) red[t] = 0.f;
    __syncthreads();

    const int rr = t >> 3, q = t & 7;
    f32x4v acc2[5];
    #pragma unroll
    for (int ht = 0; ht < 5; ++ht)
        #pragma unroll
        for (int r = 0; r < 4; ++r) acc2[ht][r] = 0.f;

    for (int kk = 0; kk < 5; ++kk) {
        {
            const float4 xv = *(const float4*)&h1s[rr * 160 + kk * 32 + q * 4];
            ushort4 hv, lv;
            split2(xv.x, hv.x, lv.x); split2(xv.y, hv.y, lv.y);
            split2(xv.z, hv.z, lv.z); split2(xv.w, hv.w, lv.w);
            *(ushort4*)&As_hi[rr * 40 + q * 4] = hv;
            *(ushort4*)&As_lo[rr * 40 + q * 4] = lv;
        }
        #pragma unroll
        for (int it = 0; it < 3; ++it) {
            const int v = t + it * 256;
            if (v < 640) {
                const int h = v >> 2, qq = v & 3;
                *(uint4*)&Bs_hi[h * 40 + qq * 8] = *(const uint4*)&AW2t_hi[h * 160 + kk * 32 + qq * 8];
                *(uint4*)&Bs_lo[h * 40 + qq * 8] = *(const uint4*)&AW2t_lo[h * 160 + kk * 32 + qq * 8];
            }
        }
        __syncthreads();
        const frag ah = *(const frag*)&As_hi[(mt + m) * 40 + quad * 8];
        const frag al = *(const frag*)&As_lo[(mt + m) * 40 + quad * 8];
        #pragma unroll
        for (int ht = 0; ht < 5; ++ht) {
            const frag bh = *(const frag*)&Bs_hi[(nb + ht * 16 + m) * 40 + quad * 8];
            const frag bl = *(const frag*)&Bs_lo[(nb + ht * 16 + m) * 40 + quad * 8];
            acc2[ht] = __builtin_amdgcn_mfma_f32_16x16x32_bf16(al, bh, acc2[ht], 0, 0, 0);
            acc2[ht] = __builtin_amdgcn_mfma_f32_16x16x32_bf16(ah, bl, acc2[ht], 0, 0, 0);
            acc2[ht] = __builtin_amdgcn_mfma_f32_16x16x32_bf16(ah, bh, acc2[ht], 0, 0, 0);
        }
        __syncthreads();
    }

    float s[4] = {0.f, 0.f, 0.f, 0.f};
    #pragma unroll
    for (int ht = 0; ht < 5; ++ht) {
        const int col = nb + ht * 16 + m;
        if (col < HIDD) {
            const float w3 = aw3[col];
            #pragma unroll
            for (int r = 0; r < 4; ++r)
                s[r] += fmaxf(acc2[ht][r] + ab2[col], 0.f) * w3;
        }
    }
    #pragma unroll
    for (int r = 0; r < 4; ++r) {
        for (int off = 8; off > 0; off >>= 1) s[r] += __shfl_down(s[r], off, 16);
    }
    if (m == 0) {
        #pragma unroll
        for (int r = 0; r < 4; ++r) atomicAdd(&red[mt + quad * 4 + r], s[r]);
    }
    __syncthreads();
    if (t < 32) attn_g[blockIdx.x * 32 + t] = red[t] + ab3[0];
}

// ---------------------------------------------------------------------------
// k_span_g: build g_i fp32 (G_ws) AND bf16 hi/lo split (Gs_hi/lo). 192 blocks.
// ---------------------------------------------------------------------------
__global__ __launch_bounds__(256) void k_span_g(
    const float* __restrict__ X, const int* __restrict__ spans,
    const float* __restrict__ attn_g, float* __restrict__ G_ws,
    u16* __restrict__ Gs_hi, u16* __restrict__ Gs_lo)
{
    __shared__ float a8[8];
    const int t  = threadIdx.x;
    const int bs = blockIdx.x;
    const int b  = bs / SS;
    const int start = spans[bs];
    const float* xb = X + ((long)b * TT + start) * EDIM;
    float* Gp = G_ws + (long)bs * E3;
    u16* Gh = Gs_hi + (long)bs * E3;
    u16* Gl = Gs_lo + (long)bs * E3;
    if (t < 8) a8[t] = attn_g[bs * 8 + t];
    __syncthreads();

    for (int e = t; e < EDIM; e += 256) {
        const float gs = xb[e];
        const float ge = xb[7 * EDIM + e];
        float ga = 0.f;
        #pragma unroll
        for (int w = 0; w < 8; ++w) ga += xb[w * EDIM + e] * a8[w];
        Gp[e] = gs; Gp[EDIM + e] = ge; Gp[2 * EDIM + e] = ga;
        u16 hi, lo;
        split2(gs, hi, lo); Gh[e] = hi;            Gl[e] = lo;
        split2(ge, hi, lo); Gh[EDIM + e] = hi;     Gl[EDIM + e] = lo;
        split2(ga, hi, lo); Gh[2 * EDIM + e] = hi; Gl[2 * EDIM + e] = lo;
    }
}

// ---------------------------------------------------------------------------
// k_heavy: FUSED pairmm + uvm (both depend only on span_g + prep).
// 1-D grid of 684 blocks:
//   [0,576): pairmm — ks=id%3, i=(id/3)%96, b=id/288. r11 code verbatim.
//   [576,684): uvm — mb=u%3, nb=(u/3)%3, kz=u/9.
// LDS: 48128-byte union (pairmm layout / uvm layout).
// ---------------------------------------------------------------------------
__global__ __launch_bounds__(256) void k_heavy(
    const float* __restrict__ G_ws,
    const u16* __restrict__ Gs_hi, const u16* __restrict__ Gs_lo,
    const u16* __restrict__ W12t_hi, const u16* __restrict__ W12t_lo,
    const u16* __restrict__ PCt_hi, const u16* __restrict__ PCt_lo,
    float* __restrict__ H1parts, float* __restrict__ UVM)
{
    __shared__ __align__(16) char smem[48128];
    const int id = blockIdx.x;
    const int t  = threadIdx.x;
    const int lane = t & 63;
    const int m    = lane & 15;
    const int quad = lane >> 4;
    const int w    = t >> 6;

    if (id < 576) {
        // ======================= pairmm (r11, 57 µs) =======================
        float* gis  = (float*)smem;                        // 768 f
        float* gjst = (float*)(smem + 3072);               // 96*32 f
        u16* As_hi  = (u16*)(smem + 15360);                // 96*32
        u16* As_lo  = (u16*)(smem + 21504);
        u16* Bs_hi  = (u16*)(smem + 27648);                // 160*32
        u16* Bs_lo  = (u16*)(smem + 37888);

        const int ks = id % 3;
        const int i  = (id / 3) % SS;
        const int b  = id / 288;
        const int ksbase = ks * 768;
        const int jt0 = i >> 4;
        const int ntiles = 6 - jt0;
        const int j0 = jt0 * 16;
        const int R  = 96 - j0;
        const int nI = R >> 3;

        const int hb   = (w & 1) * 80;
        const int apar = w >> 1;
        const int Bl_h = lane >> 2;
        const int Bl_c = lane & 3;
        const int gj_r = lane >> 3;
        const int gj_c = lane & 7;

        const float* Gi = G_ws + (long)(b * SS + i) * E3 + ksbase;
        for (int e = t; e < 768; e += 256) gis[e] = Gi[e];

        f32x4v acc[3][5];
        #pragma unroll
        for (int jt = 0; jt < 3; ++jt)
            #pragma unroll
            for (int ht = 0; ht < 5; ++ht)
                #pragma unroll
                for (int r = 0; r < 4; ++r) acc[jt][ht][r] = 0.f;

        for (int tt = 0; tt < 24; ++tt) {
            const int kk0 = ksbase + tt * 32;
            for (int q2 = w; q2 < 10; q2 += 4) {
                const int h  = q2 * 16 + Bl_h;
                const int qd = (Bl_c - (h >> 1)) & 3;
                const long so = (long)h * E3 + kk0 + qd * 8;
                async16(&PCt_hi[so], &Bs_hi[q2 * 512]);
                async16(&PCt_lo[so], &Bs_lo[q2 * 512]);
            }
            for (int g2 = w; g2 < nI; g2 += 4) {
                const int row = j0 + g2 * 8 + gj_r;
                async16(&G_ws[(long)(b * SS + row) * E3 + kk0 + gj_c * 4],
                        &gjst[g2 * 256]);
            }
            __syncthreads();

            for (int u = t; u < R * 4; u += 256) {
                const int rr = u >> 2, qd = u & 3;
                const float4 g0 = *(const float4*)&gjst[rr * 32 + qd * 8];
                const float4 g1 = *(const float4*)&gjst[rr * 32 + qd * 8 + 4];
                const int kl = tt * 32 + qd * 8;
                u16x8 hv, lv; u16 h, l;
                split2(g0.x * gis[kl + 0], h, l); hv[0] = h; lv[0] = l;
                split2(g0.y * gis[kl + 1], h, l); hv[1] = h; lv[1] = l;
                split2(g0.z * gis[kl + 2], h, l); hv[2] = h; lv[2] = l;
                split2(g0.w * gis[kl + 3], h, l); hv[3] = h; lv[3] = l;
                split2(g1.x * gis[kl + 4], h, l); hv[4] = h; lv[4] = l;
                split2(g1.y * gis[kl + 5], h, l); hv[5] = h; lv[5] = l;
                split2(g1.z * gis[kl + 6], h, l); hv[6] = h; lv[6] = l;
                split2(g1.w * gis[kl + 7], h, l); hv[7] = h; lv[7] = l;
                const int o = swzoff(rr, qd);
                *(u16x8*)&As_hi[o] = hv;
                *(u16x8*)&As_lo[o] = lv;
            }
            __syncthreads();

            frag ah[3], al[3];
            #pragma unroll
            for (int u = 0; u < 3; ++u) {
                const int a = apar + 2 * u;
                if (a < ntiles) {
                    const int o = swzoff(a * 16 + m, quad);
                    ah[u] = *(const frag*)&As_hi[o];
                    al[u] = *(const frag*)&As_lo[o];
                }
            }
            #pragma unroll
            for (int ht = 0; ht < 5; ++ht) {
                const int o = swzoff(hb + ht * 16 + m, quad);
                const frag bh = *(const frag*)&Bs_hi[o];
                const frag bl = *(const frag*)&Bs_lo[o];
                #pragma unroll
                for (int u = 0; u < 3; ++u) {
                    if (apar + 2 * u < ntiles) {
                        acc[u][ht] = __builtin_amdgcn_mfma_f32_16x16x32_bf16(al[u], bh, acc[u][ht], 0, 0, 0);
                        acc[u][ht] = __builtin_amdgcn_mfma_f32_16x16x32_bf16(ah[u], bl, acc[u][ht], 0, 0, 0);
                        acc[u][ht] = __builtin_amdgcn_mfma_f32_16x16x32_bf16(ah[u], bh, acc[u][ht], 0, 0, 0);
                    }
                }
            }
            __syncthreads();
        }

        float* dst = H1parts + (long)ks * ((long)BB * SS * SS * 160);
        #pragma unroll
        for (int u = 0; u < 3; ++u) {
            const int a = apar + 2 * u;
            if (a < ntiles) {
                #pragma unroll
                for (int ht = 0; ht < 5; ++ht) {
                    #pragma unroll
                    for (int r = 0; r < 4; ++r) {
                        const int j = (jt0 + a) * 16 + quad * 4 + r;
                        const int h = hb + ht * 16 + m;
                        dst[((long)(b * SS + i) * SS + j) * 160 + h] = acc[u][ht][r];
                    }
                }
            }
        }
    } else {
        // ========================== uvm (108 blocks) =======================
        u16* As_hi = (u16*)smem;                           // 64*40
        u16* As_lo = (u16*)(smem + 5120);
        u16* Bs_hi = (u16*)(smem + 10240);                 // 160*40
        u16* Bs_lo = (u16*)(smem + 23040);

        const int u0 = id - 576;
        const int mb = u0 % 3;
        const int nb = (u0 / 3) % 3;
        const int kz = u0 / 9;
        const int mhalf = (w & 1) * 32;
        const int nbase = (w >> 1) * 80;
        const int arr = t >> 2, aq = t & 3;

        f32x4v acc[2][5];
        #pragma unroll
        for (int i = 0; i < 2; ++i)
            #pragma unroll
            for (int j = 0; j < 5; ++j)
                #pragma unroll
                for (int r = 0; r < 4; ++r) acc[i][j][r] = 0.f;

        for (int tt = 0; tt < 6; ++tt) {
            const int kk0 = kz * 192 + tt * 32;
            *(uint4*)&As_hi[arr * 40 + aq * 8] = *(const uint4*)&Gs_hi[(long)(mb * 64 + arr) * E3 + kk0 + aq * 8];
            *(uint4*)&As_lo[arr * 40 + aq * 8] = *(const uint4*)&Gs_lo[(long)(mb * 64 + arr) * E3 + kk0 + aq * 8];
            #pragma unroll
            for (int it = 0; it < 3; ++it) {
                const int v = t + it * 256;
                if (v < 640) {
                    const int h = v >> 2, qq = v & 3;
                    *(uint4*)&Bs_hi[h * 40 + qq * 8] = *(const uint4*)&W12t_hi[(long)(nb * 160 + h) * E3 + kk0 + qq * 8];
                    *(uint4*)&Bs_lo[h * 40 + qq * 8] = *(const uint4*)&W12t_lo[(long)(nb * 160 + h) * E3 + kk0 + qq * 8];
                }
            }
            __syncthreads();
            frag ah[2], al[2];
            #pragma unroll
            for (int mt = 0; mt < 2; ++mt) {
                ah[mt] = *(const frag*)&As_hi[(mhalf + mt * 16 + m) * 40 + quad * 8];
                al[mt] = *(const frag*)&As_lo[(mhalf + mt * 16 + m) * 40 + quad * 8];
            }
            #pragma unroll
            for (int ht = 0; ht < 5; ++ht) {
                const frag bh = *(const frag*)&Bs_hi[(nbase + ht * 16 + m) * 40 + quad * 8];
                const frag bl = *(const frag*)&Bs_lo[(nbase + ht * 16 + m) * 40 + quad * 8];
                #pragma unroll
                for (int mt = 0; mt < 2; ++mt) {
                    acc[mt][ht] = __builtin_amdgcn_mfma_f32_16x16x32_bf16(al[mt], bh, acc[mt][ht], 0, 0, 0);
                    acc[mt][ht] = __builtin_amdgcn_mfma_f32_16x16x32_bf16(ah[mt], bl, acc[mt][ht], 0, 0, 0);
                    acc[mt][ht] = __builtin_amdgcn_mfma_f32_16x16x32_bf16(ah[mt], bh, acc[mt][ht], 0, 0, 0);
                }
            }
            __syncthreads();
        }
        float* dst = UVM + (long)nb * (192 * 160);
        #pragma unroll
        for (int mt = 0; mt < 2; ++mt) {
            #pragma unroll
            for (int ht = 0; ht < 5; ++ht) {
                #pragma unroll
                for (int r = 0; r < 4; ++r) {
                    const int row = mb * 64 + mhalf + mt * 16 + quad * 4 + r;
                    const int c   = nbase + ht * 16 + m;
                    atomicAdd(&dst[row * 160 + c], acc[mt][ht][r]);
                }
            }
        }
    }
}

// ---------------------------------------------------------------------------
// k_pair2: MFMA finish, 3-way j-split. Grid (3 js, 192 bi), 256 thr.
// ---------------------------------------------------------------------------
__global__ __launch_bounds__(256) void k_pair2(
    const float* __restrict__ H1parts,
    const float* __restrict__ U_ws, const float* __restrict__ V_ws,
    const float* __restrict__ pb1, const float* __restrict__ m_ws,
    const u16* __restrict__ PW2t_hi, const u16* __restrict__ PW2t_lo,
    const float* __restrict__ pb2, const float* __restrict__ pw3,
    const float* __restrict__ pb3,
    float* __restrict__ out)
{
    __shared__ __align__(16) u16 As_hi[32 * 168];
    __shared__ __align__(16) u16 As_lo[32 * 168];
    __shared__ __align__(16) u16 Bs_hi[160 * 40];
    __shared__ __align__(16) u16 Bs_lo[160 * 40];
    __shared__ float uv[160];
    __shared__ float red[32];

    const long partsz = (long)BB * SS * SS * 160;
    const int t  = threadIdx.x;
    const int js = blockIdx.x;
    const int bi = blockIdx.y;          // b*96 + i
    const int b  = bi / SS;
    const int ii = bi - b * SS;
    const int jb0 = js * 32;

    if (t < 160) uv[t] = U_ws[bi * 160 + t] + ((t < HIDD) ? pb1[t] : 0.f);
    if (t < 32) red[t] = 0.f;
    __syncthreads();

    for (int u = t; u < 32 * 40; u += 256) {
        const int jl = u / 40, hq = u - (u / 40) * 40;
        const int j  = jb0 + jl;
        const int h0 = hq * 4;
        const int mn = ii < j ? ii : j;
        const int mx = ii < j ? j : ii;
        const long idx = (((long)b * SS + mn) * SS + mx) * 160 + h0;
        const float4 vv = *(const float4*)&V_ws[(b * SS + j) * 160 + h0];
        const float4 a0 = *(const float4*)&H1parts[idx];
        const float4 a1 = *(const float4*)&H1parts[partsz + idx];
        const float4 a2 = *(const float4*)&H1parts[2 * partsz + idx];
        const float p0 = fmaxf(a0.x + a1.x + a2.x + vv.x + uv[h0 + 0], 0.f);
        const float p1 = fmaxf(a0.y + a1.y + a2.y + vv.y + uv[h0 + 1], 0.f);
        const float p2 = fmaxf(a0.z + a1.z + a2.z + vv.z + uv[h0 + 2], 0.f);
        const float p3 = fmaxf(a0.w + a1.w + a2.w + vv.w + uv[h0 + 3], 0.f);
        ushort4 hv, lv;
        split2(p0, hv.x, lv.x); split2(p1, hv.y, lv.y);
        split2(p2, hv.z, lv.z); split2(p3, hv.w, lv.w);
        *(ushort4*)&As_hi[jl * 168 + h0] = hv;
        *(ushort4*)&As_lo[jl * 168 + h0] = lv;
    }
    __syncthreads();

    const int lane = t & 63;
    const int m    = lane & 15;
    const int quad = lane >> 4;
    const int w    = t >> 6;
    const int jt   = w >> 1;
    const int nbs  = (w & 1) * 80;

    f32x4v acc[5];
    #pragma unroll
    for (int ht = 0; ht < 5; ++ht)
        #pragma unroll
        for (int r = 0; r < 4; ++r) acc[ht][r] = 0.f;

    for (int kk = 0; kk < 5; ++kk) {
        #pragma unroll
        for (int it = 0; it < 3; ++it) {
            const int v = t + it * 256;
            if (v < 640) {
                const int n = v >> 2, qq = v & 3;
                *(uint4*)&Bs_hi[n * 40 + qq * 8] = *(const uint4*)&PW2t_hi[n * 160 + kk * 32 + qq * 8];
                *(uint4*)&Bs_lo[n * 40 + qq * 8] = *(const uint4*)&PW2t_lo[n * 160 + kk * 32 + qq * 8];
            }
        }
        __syncthreads();
        const frag ah = *(const frag*)&As_hi[(jt * 16 + m) * 168 + kk * 32 + quad * 8];
        const frag al = *(const frag*)&As_lo[(jt * 16 + m) * 168 + kk * 32 + quad * 8];
        #pragma unroll
        for (int ht = 0; ht < 5; ++ht) {
            const frag bh = *(const frag*)&Bs_hi[(nbs + ht * 16 + m) * 40 + quad * 8];
            const frag bl = *(const frag*)&Bs_lo[(nbs + ht * 16 + m) * 40 + quad * 8];
            acc[ht] = __builtin_amdgcn_mfma_f32_16x16x32_bf16(al, bh, acc[ht], 0, 0, 0);
            acc[ht] = __builtin_amdgcn_mfma_f32_16x16x32_bf16(ah, bl, acc[ht], 0, 0, 0);
            acc[ht] = __builtin_amdgcn_mfma_f32_16x16x32_bf16(ah, bh, acc[ht], 0, 0, 0);
        }
        __syncthreads();
    }

    float s[4] = {0.f, 0.f, 0.f, 0.f};
    #pragma unroll
    for (int ht = 0; ht < 5; ++ht) {
        const int col = nbs + ht * 16 + m;
        if (col < HIDD) {
            const float w3 = pw3[col];
            const float b2 = pb2[col];
            #pragma unroll
            for (int r = 0; r < 4; ++r)
                s[r] += fmaxf(acc[ht][r] + b2, 0.f) * w3;
        }
    }
    #pragma unroll
    for (int r = 0; r < 4; ++r)
        for (int off = 8; off > 0; off >>= 1)
            s[r] += __shfl_down(s[r], off, 16);
    if (m == 0) {
        #pragma unroll
        for (int r = 0; r < 4; ++r)
            atomicAdd(&red[jt * 16 + quad * 4 + r], s[r]);
    }
    __syncthreads();

    if (t < 32) {
        const int j = jb0 + t;
        const float sc = red[t] + pb3[0];
        const float v = (m_ws[bi] + m_ws[b * SS + j] + sc) * (1.f / 3.f);
        out[(long)bi * SS + j] = fminf(fmaxf(v, 0.f), 1.f);
    }
}

// ---------------------------------------------------------------------------
extern "C" void kernel_launch(void* const* d_in, const int* in_sizes, int n_in,
                              void* d_out, int out_size, void* d_ws, size_t ws_size,
                              hipStream_t stream)
{
    const float* X     = (const float*)d_in[0];
    const int*   spans = (const int*)  d_in[1];
    const float* aw1 = (const float*)d_in[2];
    const float* ab1 = (const float*)d_in[3];
    const float* aw2 = (const float*)d_in[4];
    const float* ab2 = (const float*)d_in[5];
    const float* aw3 = (const float*)d_in[6];
    const float* ab3 = (const float*)d_in[7];
    const float* mw1 = (const float*)d_in[8];
    const float* mb1 = (const float*)d_in[9];
    const float* mw2 = (const float*)d_in[10];
    const float* mb2 = (const float*)d_in[11];
    const float* mw3 = (const float*)d_in[12];
    const float* mb3 = (const float*)d_in[13];
    const float* pw1 = (const float*)d_in[14];
    const float* pb1 = (const float*)d_in[15];
    const float* pw2 = (const float*)d_in[16];
    const float* pb2 = (const float*)d_in[17];
    const float* pw3 = (const float*)d_in[18];
    const float* pb3 = (const float*)d_in[19];
    float* out = (float*)d_out;

    char* p = (char*)d_ws;
    float* attn_g  = (float*)p;  p += 6144;                       // 1536 f
    float* G_ws    = (float*)p;  p += (long)442368 * 4;           // 192x2304 f
    u16*   Gs_hi   = (u16*)p;    p += (long)442368 * 2;
    u16*   Gs_lo   = (u16*)p;    p += (long)442368 * 2;
    float* UVM     = (float*)p;  p += (long)3 * 192 * 160 * 4;    // U|V|M (zeroed)
    float* AH1     = (float*)p;  p += (long)1536 * 160 * 4;       // attn L1 partials (zeroed)
    float* m_ws    = (float*)p;  p += 1024;
    u16*   W12t_hi = (u16*)p;    p += (long)640 * E3 * 2;         // PA|PB|mw1|PC
    u16*   W12t_lo = (u16*)p;    p += (long)640 * E3 * 2;
    u16*   AW1t_hi = (u16*)p;    p += (long)160 * EDIM * 2;
    u16*   AW1t_lo = (u16*)p;    p += (long)160 * EDIM * 2;
    u16*   AW2t_hi = (u16*)p;    p += 160 * 160 * 2;
    u16*   AW2t_lo = (u16*)p;    p += 160 * 160 * 2;
    u16*   PW2t_hi = (u16*)p;    p += 160 * 160 * 2;
    u16*   PW2t_lo = (u16*)p;    p += 160 * 160 * 2;
    u16*   MW2t_hi = (u16*)p;    p += 160 * 160 * 2;
    u16*   MW2t_lo = (u16*)p;    p += 160 * 160 * 2;
    float* H1parts = (float*)p;   // 3 * 11.8 MB

    float* U_ws = UVM;
    float* V_ws = UVM + 192 * 160;
    float* M_ws = UVM + 2 * 192 * 160;
    const u16* PCt_hi = W12t_hi + (long)480 * E3;
    const u16* PCt_lo = W12t_lo + (long)480 * E3;

    // zero UVM + AH1 (contiguous atomic targets)
    hipMemsetAsync(UVM, 0, ((size_t)3 * 192 * 160 + (size_t)1536 * 160) * sizeof(float), stream);

    // stage 1: only the prep that gates attn1
    k_prep_aw1<<<dim3(EDIM), 256, 0, stream>>>(aw1, AW1t_hi, AW1t_lo);

    // stage 2: attn layer-1 (288 blocks) + all remaining weight prep (1200)
    k_fused1<<<dim3(1488), 256, 0, stream>>>(X, spans, AW1t_hi, AW1t_lo, AH1,
                                             pw1, mw1, aw2, pw2, mw2,
                                             W12t_hi, W12t_lo, AW2t_hi, AW2t_lo,
                                             PW2t_hi, PW2t_lo, MW2t_hi, MW2t_lo);

    k_attn2<<<dim3(48), 256, 0, stream>>>(AH1, AW2t_hi, AW2t_lo, ab1, ab2, aw3, ab3, attn_g);
    k_span_g<<<dim3(BB * SS), 256, 0, stream>>>(X, spans, attn_g, G_ws, Gs_hi, Gs_lo);

    // fused pairmm (576 blocks) + uvm (108 blocks)
    k_heavy<<<dim3(684), 256, 0, stream>>>(G_ws, Gs_hi, Gs_lo, W12t_hi, W12t_lo,
                                           PCt_hi, PCt_lo, H1parts, UVM);

    // mention layers 2-3: identical shape to attn2 -> reuse kernel (grid 6)
    k_attn2<<<dim3(6), 256, 0, stream>>>(M_ws, MW2t_hi, MW2t_lo, mb1, mb2, mw3, mb3, m_ws);

    k_pair2<<<dim3(3, BB * SS), 256, 0, stream>>>(
        H1parts, U_ws, V_ws, pb1, m_ws, PW2t_hi, PW2t_lo, pb2, pw3, pb3, out);
}